// Round 2
// baseline (4126.366 us; speedup 1.0000x reference)
//
#include <hip/hip_runtime.h>
#include <math.h>

#define NB 32
#define NP 196
#define ENC 2048
#define ADIM 512
#define DDIM 512
#define VOC 32000
#define LCAP 40
#define TS 39

__device__ __forceinline__ float sigm(float x) { return 1.f / (1.f + expf(-x)); }

// ---------------- generic 64x64 f32 GEMM: C = A@W + bias ----------------
__global__ __launch_bounds__(256) void gemm64(
    const float* __restrict__ A, const float* __restrict__ W,
    const float* __restrict__ bias, float* __restrict__ C,
    int M, int N, int K)
{
  __shared__ float As[16][68];
  __shared__ float Ws[16][68];
  const int tid = threadIdx.x;
  const int tx = tid & 15, ty = tid >> 4;
  const int m0 = blockIdx.y * 64, n0 = blockIdx.x * 64;
  const int lm = tid >> 2, lk = (tid & 3) * 4;   // A tile: 64m x 16k
  const int wk = tid >> 4, wn = (tid & 15) * 4;  // W tile: 16k x 64n
  float acc[4][4] = {};
  for (int k0 = 0; k0 < K; k0 += 16) {
    float4 av = make_float4(0.f, 0.f, 0.f, 0.f);
    if (m0 + lm < M) av = *(const float4*)&A[(size_t)(m0 + lm) * K + k0 + lk];
    As[lk + 0][lm] = av.x; As[lk + 1][lm] = av.y; As[lk + 2][lm] = av.z; As[lk + 3][lm] = av.w;
    *(float4*)&Ws[wk][wn] = *(const float4*)&W[(size_t)(k0 + wk) * N + n0 + wn];
    __syncthreads();
#pragma unroll
    for (int k = 0; k < 16; ++k) {
      float a_[4], w_[4];
#pragma unroll
      for (int i = 0; i < 4; ++i) a_[i] = As[k][ty * 4 + i];
#pragma unroll
      for (int j = 0; j < 4; ++j) w_[j] = Ws[k][tx * 4 + j];
#pragma unroll
      for (int i = 0; i < 4; ++i)
#pragma unroll
        for (int j = 0; j < 4; ++j) acc[i][j] += a_[i] * w_[j];
    }
    __syncthreads();
  }
#pragma unroll
  for (int i = 0; i < 4; ++i) {
    int m = m0 + ty * 4 + i;
    if (m < M) {
#pragma unroll
      for (int j = 0; j < 4; ++j) {
        int n = n0 + tx * 4 + j;
        C[(size_t)m * N + n] = acc[i][j] + (bias ? bias[n] : 0.f);
      }
    }
  }
}

// ---------- embedding-gathered GEMM: C[r,:] = Emb[token(r),:]@W + b1 + b2 ----------
__global__ __launch_bounds__(256) void gemm_emb(
    const float* __restrict__ Emb, const int* __restrict__ caps,
    const float* __restrict__ W, const float* __restrict__ b1,
    const float* __restrict__ b2, float* __restrict__ C,
    int M, int N, int K)
{
  __shared__ float As[16][68];
  __shared__ float Ws[16][68];
  const int tid = threadIdx.x;
  const int tx = tid & 15, ty = tid >> 4;
  const int m0 = blockIdx.y * 64, n0 = blockIdx.x * 64;
  const int lm = tid >> 2, lk = (tid & 3) * 4;
  const int wk = tid >> 4, wn = (tid & 15) * 4;
  const int r = m0 + lm;
  const float* arow = nullptr;
  if (r < M) {
    int tt = r >> 5, bb = r & 31;  // row = t*32 + b
    arow = Emb + (size_t)caps[bb * LCAP + tt] * K;
  }
  float acc[4][4] = {};
  for (int k0 = 0; k0 < K; k0 += 16) {
    float4 av = make_float4(0.f, 0.f, 0.f, 0.f);
    if (arow) av = *(const float4*)&arow[k0 + lk];
    As[lk + 0][lm] = av.x; As[lk + 1][lm] = av.y; As[lk + 2][lm] = av.z; As[lk + 3][lm] = av.w;
    *(float4*)&Ws[wk][wn] = *(const float4*)&W[(size_t)(k0 + wk) * N + n0 + wn];
    __syncthreads();
#pragma unroll
    for (int k = 0; k < 16; ++k) {
      float a_[4], w_[4];
#pragma unroll
      for (int i = 0; i < 4; ++i) a_[i] = As[k][ty * 4 + i];
#pragma unroll
      for (int j = 0; j < 4; ++j) w_[j] = Ws[k][tx * 4 + j];
#pragma unroll
      for (int i = 0; i < 4; ++i)
#pragma unroll
        for (int j = 0; j < 4; ++j) acc[i][j] += a_[i] * w_[j];
    }
    __syncthreads();
  }
#pragma unroll
  for (int i = 0; i < 4; ++i) {
    int m = m0 + ty * 4 + i;
    if (m < M) {
#pragma unroll
      for (int j = 0; j < 4; ++j) {
        int n = n0 + tx * 4 + j;
        C[(size_t)m * N + n] = acc[i][j] + b1[n] + b2[n];
      }
    }
  }
}

// ---------------- avg over P ----------------
__global__ __launch_bounds__(256) void avgk(const float* __restrict__ enc, float* __restrict__ avg)
{
  int idx = blockIdx.x * 256 + threadIdx.x;   // 32*2048
  int b = idx >> 11, e = idx & 2047;
  float s = 0.f;
  for (int p = 0; p < NP; ++p) s += enc[(size_t)(b * NP + p) * ENC + e];
  avg[idx] = s * (1.f / 196.f);
}

// ---------- shared 32x64 K-chunk tile GEMM on A = 32 x lda rows ----------
__device__ __forceinline__ void tile32x64(
    const float* __restrict__ Arows, int lda,
    const float* __restrict__ W, int ldw, int ncol,
    int k_begin, int k_end,
    float (*As)[33], float (*Ws)[68], float acc[2][4])
{
  const int tid = threadIdx.x;
  const int tx = tid & 15, ty = tid >> 4;
  const int lm = tid >> 3, lk = (tid & 7) * 4;   // 32m x 32k
  const int wk = tid >> 4, wn = (tid & 15) * 4;  // 32k x 64n (2 rows/thread)
  for (int k0 = k_begin; k0 < k_end; k0 += 32) {
    float4 av = *(const float4*)&Arows[lm * lda + k0 + lk];
    As[lk + 0][lm] = av.x; As[lk + 1][lm] = av.y; As[lk + 2][lm] = av.z; As[lk + 3][lm] = av.w;
    *(float4*)&Ws[wk][wn]      = *(const float4*)&W[(size_t)(k0 + wk) * ldw + ncol + wn];
    *(float4*)&Ws[wk + 16][wn] = *(const float4*)&W[(size_t)(k0 + wk + 16) * ldw + ncol + wn];
    __syncthreads();
#pragma unroll
    for (int k = 0; k < 32; ++k) {
      float a0 = As[k][ty * 2], a1 = As[k][ty * 2 + 1];
      float4 w = *(const float4*)&Ws[k][tx * 4];
      acc[0][0] += a0 * w.x; acc[0][1] += a0 * w.y; acc[0][2] += a0 * w.z; acc[0][3] += a0 * w.w;
      acc[1][0] += a1 * w.x; acc[1][1] += a1 * w.y; acc[1][2] += a1 * w.z; acc[1][3] += a1 * w.w;
    }
    __syncthreads();
  }
}

// ---------------- K1: dec+gate partials P1[s][b][j], j in [0,2560) ----------------
__device__ void k1_body(int nb, int s, const float* __restrict__ h,
                        const float* __restrict__ Wd, const float* __restrict__ Wfb,
                        float* __restrict__ P1, float (*As)[33], float (*Ws)[68])
{
  int n0 = nb * 64;
  const float* W; int ldw, ncol;
  if (n0 < 512) { W = Wd; ldw = 512; ncol = n0; }
  else          { W = Wfb; ldw = 2048; ncol = n0 - 512; }
  float acc[2][4] = {};
  tile32x64(h, 512, W, ldw, ncol, s * 128, s * 128 + 128, As, Ws, acc);
  int tx = threadIdx.x & 15, ty = threadIdx.x >> 4;
#pragma unroll
  for (int i = 0; i < 2; ++i)
#pragma unroll
    for (int j = 0; j < 4; ++j)
      P1[s * (32 * 2560) + (ty * 2 + i) * 2560 + n0 + tx * 4 + j] = acc[i][j];
}

__global__ __launch_bounds__(256) void k1_decgate(
    const float* __restrict__ h, const float* __restrict__ Wd,
    const float* __restrict__ Wfb, float* __restrict__ P1)
{
  __shared__ float As[32][33];
  __shared__ float Ws[32][68];
  k1_body(blockIdx.x, blockIdx.y, h, Wd, Wfb, P1, As, Ws);
}

// ---------------- K2: attention per batch row ----------------
__global__ __launch_bounds__(256) void k2_attn(
    const float* __restrict__ P1, const float* __restrict__ bdec, const float* __restrict__ bfb,
    const float* __restrict__ watt, const float* __restrict__ batt,
    const float* __restrict__ encatt, const float* __restrict__ enc,
    const int* __restrict__ clen, float* __restrict__ outa, float* __restrict__ aweg, int t)
{
  int b = blockIdx.x, tid = threadIdx.x;
  __shared__ float dec_s[512], watt_s[512], al_s[196], red_s[256];
  for (int a = tid; a < 512; a += 256) {
    float v = bdec[a];
#pragma unroll
    for (int s = 0; s < 4; ++s) v += P1[s * (32 * 2560) + b * 2560 + a];
    dec_s[a] = v;
    watt_s[a] = watt[a];
  }
  __syncthreads();
  float e = -1e30f;
  if (tid < NP) {
    const float* row = encatt + (size_t)(b * NP + tid) * 512;
    float acc = 0.f;
    for (int a = 0; a < 512; a += 4) {
      float4 ev = *(const float4*)&row[a];
      acc += fmaxf(ev.x + dec_s[a + 0], 0.f) * watt_s[a + 0];
      acc += fmaxf(ev.y + dec_s[a + 1], 0.f) * watt_s[a + 1];
      acc += fmaxf(ev.z + dec_s[a + 2], 0.f) * watt_s[a + 2];
      acc += fmaxf(ev.w + dec_s[a + 3], 0.f) * watt_s[a + 3];
    }
    e = acc + batt[0];
  }
  red_s[tid] = e;
  __syncthreads();
  for (int w = 128; w > 0; w >>= 1) {
    if (tid < w) red_s[tid] = fmaxf(red_s[tid], red_s[tid + w]);
    __syncthreads();
  }
  float m = red_s[0];
  __syncthreads();
  float ex = (tid < NP) ? expf(e - m) : 0.f;
  red_s[tid] = ex;
  __syncthreads();
  for (int w = 128; w > 0; w >>= 1) {
    if (tid < w) red_s[tid] += red_s[tid + w];
    __syncthreads();
  }
  float inv = 1.f / red_s[0];
  bool act = clen[b] - 1 > t;
  if (tid < NP) {
    float al = ex * inv;
    al_s[tid] = al;
    outa[(size_t)(b * TS + t) * NP + tid] = act ? al : 0.f;
  }
  __syncthreads();
  // awe (alpha-weighted encoder sum), gated; vectorized over d
#pragma unroll
  for (int it = 0; it < 2; ++it) {
    int d = (it * 256 + tid) * 4;
    float ax = 0.f, ay = 0.f, az = 0.f, aw = 0.f;
    for (int p = 0; p < NP; ++p) {
      float al = al_s[p];
      float4 ev = *(const float4*)&enc[(size_t)(b * NP + p) * ENC + d];
      ax += al * ev.x; ay += al * ev.y; az += al * ev.z; aw += al * ev.w;
    }
    float gx = bfb[d + 0], gy = bfb[d + 1], gz = bfb[d + 2], gw = bfb[d + 3];
#pragma unroll
    for (int s = 0; s < 4; ++s) {
      const float* p1 = P1 + s * (32 * 2560) + b * 2560 + 512 + d;
      gx += p1[0]; gy += p1[1]; gz += p1[2]; gw += p1[3];
    }
    float4 o;
    o.x = sigm(gx) * ax; o.y = sigm(gy) * ay; o.z = sigm(gz) * az; o.w = sigm(gw) * aw;
    *(float4*)&aweg[b * ENC + d] = o;
  }
}

// ---------------- K3: g partials over K = 2048(awe) + 512(h) ----------------
__global__ __launch_bounds__(256) void k3_g(
    const float* __restrict__ aweg, const float* __restrict__ h,
    const float* __restrict__ Wih, const float* __restrict__ Whh,
    float* __restrict__ P2)
{
  __shared__ float As[32][33];
  __shared__ float Ws[32][68];
  const int n0 = blockIdx.x * 64;
  const int s = blockIdx.y;
  const int tid = threadIdx.x;
  const int tx = tid & 15, ty = tid >> 4;
  const int lm = tid >> 3, lk = (tid & 7) * 4;
  const int wk = tid >> 4, wn = (tid & 15) * 4;
  float acc[2][4] = {};
  for (int k0 = s * 320; k0 < s * 320 + 320; k0 += 32) {
    const float* Ab; int lda, kb; const float* Wb;
    if (k0 < 2048) { Ab = aweg; lda = 2048; kb = k0; Wb = Wih + (size_t)(512 + k0) * 2048; }
    else           { Ab = h;    lda = 512;  kb = k0 - 2048; Wb = Whh + (size_t)(k0 - 2048) * 2048; }
    float4 av = *(const float4*)&Ab[lm * lda + kb + lk];
    As[lk + 0][lm] = av.x; As[lk + 1][lm] = av.y; As[lk + 2][lm] = av.z; As[lk + 3][lm] = av.w;
    *(float4*)&Ws[wk][wn]      = *(const float4*)&Wb[(size_t)wk * 2048 + n0 + wn];
    *(float4*)&Ws[wk + 16][wn] = *(const float4*)&Wb[(size_t)(wk + 16) * 2048 + n0 + wn];
    __syncthreads();
#pragma unroll
    for (int k = 0; k < 32; ++k) {
      float a0 = As[k][ty * 2], a1 = As[k][ty * 2 + 1];
      float4 w = *(const float4*)&Ws[k][tx * 4];
      acc[0][0] += a0 * w.x; acc[0][1] += a0 * w.y; acc[0][2] += a0 * w.z; acc[0][3] += a0 * w.w;
      acc[1][0] += a1 * w.x; acc[1][1] += a1 * w.y; acc[1][2] += a1 * w.z; acc[1][3] += a1 * w.w;
    }
    __syncthreads();
  }
#pragma unroll
  for (int i = 0; i < 2; ++i)
#pragma unroll
    for (int j = 0; j < 4; ++j)
      P2[s * (32 * 2048) + (ty * 2 + i) * 2048 + n0 + tx * 4 + j] = acc[i][j];
}

// ---------------- K4: reduce partials + LSTM pointwise + state update ----------------
__global__ __launch_bounds__(256) void k4_lstm(
    const float* __restrict__ P2, const float* __restrict__ embproj,
    const int* __restrict__ clen, float* __restrict__ h, float* __restrict__ c, int t)
{
  int idx = blockIdx.x * 256 + threadIdx.x;  // 32*512
  int b = idx >> 9, d = idx & 511;
  const float* ep = embproj + (size_t)(t * 32 + b) * 2048;
  float i_ = ep[d], f_ = ep[512 + d], g_ = ep[1024 + d], o_ = ep[1536 + d];
#pragma unroll
  for (int s = 0; s < 8; ++s) {
    const float* p2 = P2 + s * (32 * 2048) + b * 2048;
    i_ += p2[d]; f_ += p2[512 + d]; g_ += p2[1024 + d]; o_ += p2[1536 + d];
  }
  float cv = c[idx];
  float cn = sigm(f_) * cv + sigm(i_) * tanhf(g_);
  float hn = sigm(o_) * tanhf(cn);
  if (clen[b] - 1 > t) { h[idx] = hn; c[idx] = cn; }
}

// ---------------- KM: preds(t) [blocks 0..499] + K1(t+1) [blocks 500..659] ----------------
__global__ __launch_bounds__(256) void km_preds_k1(
    const float* __restrict__ h, const float* __restrict__ Wfc, const float* __restrict__ bfc,
    const int* __restrict__ clen, float* __restrict__ outp, int t,
    const float* __restrict__ Wd, const float* __restrict__ Wfb, float* __restrict__ P1,
    int do_k1)
{
  __shared__ float As[32][33];
  __shared__ float Ws[32][68];
  int bid = blockIdx.x;
  if (bid < 500) {
    int n0 = bid * 64;
    float acc[2][4] = {};
    tile32x64(h, 512, Wfc, VOC, n0, 0, 512, As, Ws, acc);
    int tx = threadIdx.x & 15, ty = threadIdx.x >> 4;
#pragma unroll
    for (int i = 0; i < 2; ++i) {
      int b = ty * 2 + i;
      bool act = clen[b] - 1 > t;
#pragma unroll
      for (int j = 0; j < 4; ++j) {
        int n = n0 + tx * 4 + j;
        outp[(size_t)b * (TS * VOC) + (size_t)t * VOC + n] = act ? (acc[i][j] + bfc[n]) : 0.f;
      }
    }
  } else if (do_k1) {
    int i2 = bid - 500;
    k1_body(i2 % 40, i2 / 40, h, Wd, Wfb, P1, As, Ws);
  }
}

extern "C" void kernel_launch(void* const* d_in, const int* in_sizes, int n_in,
                              void* d_out, int out_size, void* d_ws, size_t ws_size,
                              hipStream_t stream)
{
  (void)in_sizes; (void)n_in; (void)out_size; (void)ws_size;
  const float* enc   = (const float*)d_in[0];
  const int*   caps  = (const int*)d_in[1];
  const int*   clen  = (const int*)d_in[2];
  const float* emb   = (const float*)d_in[3];
  const float* W_enc = (const float*)d_in[4];
  const float* b_enc = (const float*)d_in[5];
  const float* W_dec = (const float*)d_in[6];
  const float* b_dec = (const float*)d_in[7];
  const float* w_att = (const float*)d_in[8];
  const float* b_att = (const float*)d_in[9];
  const float* W_ih  = (const float*)d_in[10];
  const float* b_ih  = (const float*)d_in[11];
  const float* W_hh  = (const float*)d_in[12];
  const float* b_hh  = (const float*)d_in[13];
  const float* W_h   = (const float*)d_in[14];
  const float* b_h   = (const float*)d_in[15];
  const float* W_c   = (const float*)d_in[16];
  const float* b_c   = (const float*)d_in[17];
  const float* W_fb  = (const float*)d_in[18];
  const float* b_fb  = (const float*)d_in[19];
  const float* W_fc  = (const float*)d_in[20];
  const float* b_fc  = (const float*)d_in[21];

  float* out_preds = (float*)d_out;
  float* out_alpha = out_preds + (size_t)NB * TS * VOC;

  float* ws      = (float*)d_ws;
  float* avg     = ws;                      // 32*2048
  float* h       = avg + 65536;             // 32*512
  float* c       = h + 16384;               // 32*512
  float* encatt  = c + 16384;               // 32*196*512
  float* embproj = encatt + 3211264;        // 39*32*2048
  float* P1buf   = embproj + 2555904;       // 4*32*2560
  float* aweg    = P1buf + 327680;          // 32*2048
  float* P2buf   = aweg + 65536;            // 8*32*2048

  avgk<<<dim3(256), 256, 0, stream>>>(enc, avg);
  gemm64<<<dim3(8, 1), 256, 0, stream>>>(avg, W_h, b_h, h, 32, 512, 2048);
  gemm64<<<dim3(8, 1), 256, 0, stream>>>(avg, W_c, b_c, c, 32, 512, 2048);
  gemm64<<<dim3(8, 98), 256, 0, stream>>>(enc, W_enc, b_enc, encatt, 6272, 512, 2048);
  gemm_emb<<<dim3(32, 20), 256, 0, stream>>>(emb, caps, W_ih, b_ih, b_hh, embproj, 1248, 2048, 512);
  k1_decgate<<<dim3(40, 4), 256, 0, stream>>>(h, W_dec, W_fb, P1buf);

  for (int t = 0; t < TS; ++t) {
    k2_attn<<<dim3(32), 256, 0, stream>>>(P1buf, b_dec, b_fb, w_att, b_att,
                                          encatt, enc, clen, out_alpha, aweg, t);
    k3_g<<<dim3(32, 8), 256, 0, stream>>>(aweg, h, W_ih, W_hh, P2buf);
    k4_lstm<<<dim3(64), 256, 0, stream>>>(P2buf, embproj, clen, h, c, t);
    km_preds_k1<<<dim3(660), 256, 0, stream>>>(h, W_fc, b_fc, clen, out_preds, t,
                                               W_dec, W_fb, P1buf, (t < TS - 1) ? 1 : 0);
  }
}

// Round 3
// 4076.390 us; speedup vs baseline: 1.0123x; 1.0123x over previous
//
#include <hip/hip_runtime.h>
#include <math.h>

#define NB 32
#define NP 196
#define ENC 2048
#define ADIM 512
#define DDIM 512
#define VOC 32000
#define LCAP 40
#define TS 39

typedef unsigned int uint_t;
typedef unsigned short ushort_t;

__device__ __forceinline__ float sigm(float x) { return 1.f / (1.f + expf(-x)); }

// ---------- bf16 helpers (RNE, bit-exact, header-independent) ----------
__device__ __forceinline__ ushort_t f2bf(float f) {
  uint_t u = __float_as_uint(f);
  u = (u + 0x7FFFu + ((u >> 16) & 1u)) >> 16;
  return (ushort_t)u;
}
__device__ __forceinline__ float bf2f(ushort_t s) { return __uint_as_float(((uint_t)s) << 16); }

typedef __attribute__((ext_vector_type(8))) short bf8v;
typedef __attribute__((ext_vector_type(16))) float f16v;

__device__ __forceinline__ f16v MFMA(bf8v a, bf8v b, f16v c) {
  return __builtin_amdgcn_mfma_f32_32x32x16_bf16(a, b, c, 0, 0, 0);
}

// =====================================================================
// MFMA core: one wave computes C[32 x 32cols] over k-range, split-bf16
// A: [32][ldA] bf16 hi/lo (row-major). A0 for k<kbound, A1 after.
// W_t: [N][ldW] bf16 hi/lo (row n = output col, contiguous in k).
// Layout: A row = lane&31, k = 8*(lane>>5)+e; B col = lane&31, same k.
// =====================================================================
__device__ __forceinline__ void mfma32_core(
    const ushort_t* __restrict__ A0hi, const ushort_t* __restrict__ A0lo, int ldA0,
    const ushort_t* __restrict__ A1hi, const ushort_t* __restrict__ A1lo, int ldA1,
    int kbound,
    const ushort_t* __restrict__ Whi, const ushort_t* __restrict__ Wlo, int ldW,
    int col0, int kbeg, int kend, f16v& acc)
{
  const int lane = threadIdx.x & 63;
  const int r = lane & 31;
  const int g = lane >> 5;
  const ushort_t* wh = Whi + (size_t)(col0 + r) * ldW + g * 8;
  const ushort_t* wl = Wlo + (size_t)(col0 + r) * ldW + g * 8;
#pragma unroll 2
  for (int k0 = kbeg; k0 < kend; k0 += 16) {
    const ushort_t* ah; const ushort_t* al; int ld, kk;
    if (k0 < kbound) { ah = A0hi; al = A0lo; ld = ldA0; kk = k0; }
    else             { ah = A1hi; al = A1lo; ld = ldA1; kk = k0 - kbound; }
    bf8v avh = *reinterpret_cast<const bf8v*>(ah + (size_t)r * ld + kk + g * 8);
    bf8v avl = *reinterpret_cast<const bf8v*>(al + (size_t)r * ld + kk + g * 8);
    bf8v bvh = *reinterpret_cast<const bf8v*>(wh + k0);
    bf8v bvl = *reinterpret_cast<const bf8v*>(wl + k0);
    acc = MFMA(avh, bvh, acc);
    acc = MFMA(avh, bvl, acc);
    acc = MFMA(avl, bvh, acc);
  }
}

// C/D mapping (HW-verified): col = lane&31, row = (reg&3)+8*(reg>>2)+4*(lane>>5)
#define CD_ROW(rr, g) (((rr) & 3) + 8 * ((rr) >> 2) + 4 * (g))

// ---------------- enc_att: encatt = enc @ W_enc + b_enc ----------------
__global__ __launch_bounds__(256) void menc_att(
    const ushort_t* __restrict__ Ahi, const ushort_t* __restrict__ Alo,
    const ushort_t* __restrict__ Whi, const ushort_t* __restrict__ Wlo,
    const float* __restrict__ benc, float* __restrict__ encatt)
{
  int w = threadIdx.x >> 6;
  int m0 = blockIdx.y * 32;
  int col0 = blockIdx.x * 128 + w * 32;
  f16v acc = (f16v)(0.0f);
  mfma32_core(Ahi + (size_t)m0 * ENC, Alo + (size_t)m0 * ENC, ENC,
              Ahi, Alo, ENC, 1 << 30, Whi, Wlo, ENC, col0, 0, ENC, acc);
  int lane = threadIdx.x & 63, r = lane & 31, g = lane >> 5;
  int n = col0 + r;
  float bn = benc[n];
#pragma unroll
  for (int rr = 0; rr < 16; ++rr)
    encatt[(size_t)(m0 + CD_ROW(rr, g)) * 512 + n] = acc[rr] + bn;
}

// ---------------- k1: dec_gate = h @ [W_dec | W_fb] ----------------
__global__ __launch_bounds__(256) void mk1(
    const ushort_t* __restrict__ hhi, const ushort_t* __restrict__ hlo,
    const ushort_t* __restrict__ W1hi, const ushort_t* __restrict__ W1lo,
    float* __restrict__ dec_gate)
{
  int w = threadIdx.x >> 6;
  int col0 = blockIdx.x * 128 + w * 32;
  f16v acc = (f16v)(0.0f);
  mfma32_core(hhi, hlo, 512, hhi, hlo, 512, 1 << 30, W1hi, W1lo, 512, col0, 0, 512, acc);
  int lane = threadIdx.x & 63, r = lane & 31, g = lane >> 5;
  int n = col0 + r;
#pragma unroll
  for (int rr = 0; rr < 16; ++rr)
    dec_gate[CD_ROW(rr, g) * 2560 + n] = acc[rr];
}

// ---------------- k3: P2[s] = partial of [aweg|h] @ [W_ih(awe)|W_hh] ----------------
__global__ __launch_bounds__(256) void mk3(
    const ushort_t* __restrict__ awehi, const ushort_t* __restrict__ awelo,
    const ushort_t* __restrict__ hhi, const ushort_t* __restrict__ hlo,
    const ushort_t* __restrict__ W3hi, const ushort_t* __restrict__ W3lo,
    float* __restrict__ P2)
{
  int w = threadIdx.x >> 6;
  int col0 = blockIdx.x * 128 + w * 32;
  int s = blockIdx.y;
  f16v acc = (f16v)(0.0f);
  mfma32_core(awehi, awelo, 2048, hhi, hlo, 512, 2048,
              W3hi, W3lo, 2560, col0, s * 320, s * 320 + 320, acc);
  int lane = threadIdx.x & 63, r = lane & 31, g = lane >> 5;
  int n = col0 + r;
#pragma unroll
  for (int rr = 0; rr < 16; ++rr)
    P2[(size_t)s * (32 * 2048) + CD_ROW(rr, g) * 2048 + n] = acc[rr];
}

// ---------------- km: preds(t) [0..249] + k1(t+1) [250..269] ----------------
__global__ __launch_bounds__(256) void mkm(
    const ushort_t* __restrict__ hhi, const ushort_t* __restrict__ hlo,
    const ushort_t* __restrict__ Wfchi, const ushort_t* __restrict__ Wfclo,
    const float* __restrict__ bfc, const int* __restrict__ clen,
    float* __restrict__ outp, int t,
    const ushort_t* __restrict__ W1hi, const ushort_t* __restrict__ W1lo,
    float* __restrict__ dec_gate, int do_k1)
{
  int bid = blockIdx.x;
  int w = threadIdx.x >> 6;
  int lane = threadIdx.x & 63, r = lane & 31, g = lane >> 5;
  if (bid < 250) {
    int col0 = bid * 128 + w * 32;
    f16v acc = (f16v)(0.0f);
    mfma32_core(hhi, hlo, 512, hhi, hlo, 512, 1 << 30, Wfchi, Wfclo, 512, col0, 0, 512, acc);
    int n = col0 + r;
    float bn = bfc[n];
#pragma unroll
    for (int rr = 0; rr < 16; ++rr) {
      int b = CD_ROW(rr, g);
      bool act = clen[b] - 1 > t;
      outp[(size_t)b * (TS * VOC) + (size_t)t * VOC + n] = act ? (acc[rr] + bn) : 0.f;
    }
  } else if (do_k1) {
    int col0 = (bid - 250) * 128 + w * 32;
    f16v acc = (f16v)(0.0f);
    mfma32_core(hhi, hlo, 512, hhi, hlo, 512, 1 << 30, W1hi, W1lo, 512, col0, 0, 512, acc);
    int n = col0 + r;
#pragma unroll
    for (int rr = 0; rr < 16; ++rr)
      dec_gate[CD_ROW(rr, g) * 2560 + n] = acc[rr];
  }
}

// ---------------- conversions ----------------
// elementwise f32 -> bf16 hi/lo pair
__global__ __launch_bounds__(256) void convA(
    const float* __restrict__ src, ushort_t* __restrict__ dhi,
    ushort_t* __restrict__ dlo, int n4)
{
  int i = blockIdx.x * 256 + threadIdx.x;
  if (i >= n4) return;
  float4 v = *(const float4*)&src[(size_t)i * 4];
  ushort4 hi, lo;
  hi.x = f2bf(v.x); lo.x = f2bf(v.x - bf2f(hi.x));
  hi.y = f2bf(v.y); lo.y = f2bf(v.y - bf2f(hi.y));
  hi.z = f2bf(v.z); lo.z = f2bf(v.z - bf2f(hi.z));
  hi.w = f2bf(v.w); lo.w = f2bf(v.w - bf2f(hi.w));
  *(ushort4*)&dhi[(size_t)i * 4] = hi;
  *(ushort4*)&dlo[(size_t)i * 4] = lo;
}

// transpose-convert: src [K][srcN] f32  ->  dst [n][k] bf16 hi/lo (ld = dld)
__global__ __launch_bounds__(256) void convT(
    const float* __restrict__ src, int srcN,
    ushort_t* __restrict__ dhi, ushort_t* __restrict__ dlo, int dld)
{
  __shared__ float t_s[32][36];
  int n0 = blockIdx.x * 32, k0 = blockIdx.y * 32;
  int r = threadIdx.x >> 3, c4 = (threadIdx.x & 7) * 4;
  float4 v = *(const float4*)&src[(size_t)(k0 + r) * srcN + n0 + c4];
  t_s[r][c4 + 0] = v.x; t_s[r][c4 + 1] = v.y; t_s[r][c4 + 2] = v.z; t_s[r][c4 + 3] = v.w;
  __syncthreads();
  float f0 = t_s[c4 + 0][r], f1 = t_s[c4 + 1][r], f2 = t_s[c4 + 2][r], f3 = t_s[c4 + 3][r];
  ushort4 hi, lo;
  hi.x = f2bf(f0); lo.x = f2bf(f0 - bf2f(hi.x));
  hi.y = f2bf(f1); lo.y = f2bf(f1 - bf2f(hi.y));
  hi.z = f2bf(f2); lo.z = f2bf(f2 - bf2f(hi.z));
  hi.w = f2bf(f3); lo.w = f2bf(f3 - bf2f(hi.w));
  *(ushort4*)&dhi[(size_t)(n0 + r) * dld + k0 + c4] = hi;
  *(ushort4*)&dlo[(size_t)(n0 + r) * dld + k0 + c4] = lo;
}

// ---------------- k2: attention (grid 32 x 4 d-slices) ----------------
__global__ __launch_bounds__(256) void k2_attn2(
    const float* __restrict__ dec_gate, const float* __restrict__ bdec,
    const float* __restrict__ bfb, const float* __restrict__ watt,
    const float* __restrict__ batt, const float* __restrict__ encatt,
    const float* __restrict__ enc, const int* __restrict__ clen,
    float* __restrict__ outa, ushort_t* __restrict__ awehi,
    ushort_t* __restrict__ awelo, int t)
{
  int b = blockIdx.x, ds = blockIdx.y, tid = threadIdx.x;
  __shared__ float dec_s[512], watt_s[512], al_s[196], red_s[256], aw_s[128][4];
  for (int a = tid; a < 512; a += 256) {
    dec_s[a] = dec_gate[b * 2560 + a] + bdec[a];
    watt_s[a] = watt[a];
  }
  __syncthreads();
  float e = -1e30f;
  if (tid < NP) {
    const float* row = encatt + (size_t)(b * NP + tid) * 512;
    float acc = 0.f;
    for (int a = 0; a < 512; a += 4) {
      float4 ev = *(const float4*)&row[a];
      acc += fmaxf(ev.x + dec_s[a + 0], 0.f) * watt_s[a + 0];
      acc += fmaxf(ev.y + dec_s[a + 1], 0.f) * watt_s[a + 1];
      acc += fmaxf(ev.z + dec_s[a + 2], 0.f) * watt_s[a + 2];
      acc += fmaxf(ev.w + dec_s[a + 3], 0.f) * watt_s[a + 3];
    }
    e = acc + batt[0];
  }
  red_s[tid] = e;
  __syncthreads();
  for (int w = 128; w > 0; w >>= 1) {
    if (tid < w) red_s[tid] = fmaxf(red_s[tid], red_s[tid + w]);
    __syncthreads();
  }
  float m = red_s[0];
  __syncthreads();
  float ex = (tid < NP) ? expf(e - m) : 0.f;
  red_s[tid] = ex;
  __syncthreads();
  for (int w = 128; w > 0; w >>= 1) {
    if (tid < w) red_s[tid] += red_s[tid + w];
    __syncthreads();
  }
  float inv = 1.f / red_s[0];
  bool act = clen[b] - 1 > t;
  if (tid < NP) {
    float al = ex * inv;
    al_s[tid] = al;
    if (ds == 0) outa[(size_t)(b * TS + t) * NP + tid] = act ? al : 0.f;
  }
  __syncthreads();
  // awe over this block's 512-col slice; 2-way p-split per quad
  int q = tid & 127, half = tid >> 7;
  int d = ds * 512 + q * 4;
  float ax = 0.f, ay = 0.f, az = 0.f, aw = 0.f;
  int p0 = half * 98;
#pragma unroll 4
  for (int p = p0; p < p0 + 98; ++p) {
    float al = al_s[p];
    float4 ev = *(const float4*)&enc[(size_t)(b * NP + p) * ENC + d];
    ax += al * ev.x; ay += al * ev.y; az += al * ev.z; aw += al * ev.w;
  }
  if (half == 0) { aw_s[q][0] = ax; aw_s[q][1] = ay; aw_s[q][2] = az; aw_s[q][3] = aw; }
  __syncthreads();
  if (half == 1) {
    ax += aw_s[q][0]; ay += aw_s[q][1]; az += aw_s[q][2]; aw += aw_s[q][3];
    float g0 = dec_gate[b * 2560 + 512 + d + 0] + bfb[d + 0];
    float g1 = dec_gate[b * 2560 + 512 + d + 1] + bfb[d + 1];
    float g2 = dec_gate[b * 2560 + 512 + d + 2] + bfb[d + 2];
    float g3 = dec_gate[b * 2560 + 512 + d + 3] + bfb[d + 3];
    float v0 = sigm(g0) * ax, v1 = sigm(g1) * ay, v2 = sigm(g2) * az, v3 = sigm(g3) * aw;
    ushort4 hi, lo;
    hi.x = f2bf(v0); lo.x = f2bf(v0 - bf2f(hi.x));
    hi.y = f2bf(v1); lo.y = f2bf(v1 - bf2f(hi.y));
    hi.z = f2bf(v2); lo.z = f2bf(v2 - bf2f(hi.z));
    hi.w = f2bf(v3); lo.w = f2bf(v3 - bf2f(hi.w));
    *(ushort4*)&awehi[b * 2048 + d] = hi;
    *(ushort4*)&awelo[b * 2048 + d] = lo;
  }
}

// ---------------- k4: LSTM pointwise + h bf16-pair state ----------------
__global__ __launch_bounds__(256) void k4_lstm2(
    const float* __restrict__ P2, const float* __restrict__ embproj,
    const int* __restrict__ clen, float* __restrict__ c,
    ushort_t* __restrict__ hhi, ushort_t* __restrict__ hlo, int t)
{
  int idx = blockIdx.x * 256 + threadIdx.x;  // 32*512
  int b = idx >> 9, d = idx & 511;
  const float* ep = embproj + (size_t)(t * 32 + b) * 2048;
  float i_ = ep[d], f_ = ep[512 + d], g_ = ep[1024 + d], o_ = ep[1536 + d];
#pragma unroll
  for (int s = 0; s < 8; ++s) {
    const float* p2 = P2 + (size_t)s * (32 * 2048) + b * 2048;
    i_ += p2[d]; f_ += p2[512 + d]; g_ += p2[1024 + d]; o_ += p2[1536 + d];
  }
  float cv = c[idx];
  float cn = sigm(f_) * cv + sigm(i_) * tanhf(g_);
  float hn = sigm(o_) * tanhf(cn);
  if (clen[b] - 1 > t) {
    c[idx] = cn;
    ushort_t hh = f2bf(hn);
    hhi[idx] = hh;
    hlo[idx] = f2bf(hn - bf2f(hh));
  }
}

// =====================================================================
// ============ old f32 path (fallback if ws too small) ================
// =====================================================================
__global__ __launch_bounds__(256) void gemm64(
    const float* __restrict__ A, const float* __restrict__ W,
    const float* __restrict__ bias, float* __restrict__ C,
    int M, int N, int K)
{
  __shared__ float As[16][68];
  __shared__ float Ws[16][68];
  const int tid = threadIdx.x;
  const int tx = tid & 15, ty = tid >> 4;
  const int m0 = blockIdx.y * 64, n0 = blockIdx.x * 64;
  const int lm = tid >> 2, lk = (tid & 3) * 4;
  const int wk = tid >> 4, wn = (tid & 15) * 4;
  float acc[4][4] = {};
  for (int k0 = 0; k0 < K; k0 += 16) {
    float4 av = make_float4(0.f, 0.f, 0.f, 0.f);
    if (m0 + lm < M) av = *(const float4*)&A[(size_t)(m0 + lm) * K + k0 + lk];
    As[lk + 0][lm] = av.x; As[lk + 1][lm] = av.y; As[lk + 2][lm] = av.z; As[lk + 3][lm] = av.w;
    *(float4*)&Ws[wk][wn] = *(const float4*)&W[(size_t)(k0 + wk) * N + n0 + wn];
    __syncthreads();
#pragma unroll
    for (int k = 0; k < 16; ++k) {
      float a_[4], w_[4];
#pragma unroll
      for (int i = 0; i < 4; ++i) a_[i] = As[k][ty * 4 + i];
#pragma unroll
      for (int j = 0; j < 4; ++j) w_[j] = Ws[k][tx * 4 + j];
#pragma unroll
      for (int i = 0; i < 4; ++i)
#pragma unroll
        for (int j = 0; j < 4; ++j) acc[i][j] += a_[i] * w_[j];
    }
    __syncthreads();
  }
#pragma unroll
  for (int i = 0; i < 4; ++i) {
    int m = m0 + ty * 4 + i;
    if (m < M) {
#pragma unroll
      for (int j = 0; j < 4; ++j) {
        int n = n0 + tx * 4 + j;
        C[(size_t)m * N + n] = acc[i][j] + (bias ? bias[n] : 0.f);
      }
    }
  }
}

__global__ __launch_bounds__(256) void gemm_emb(
    const float* __restrict__ Emb, const int* __restrict__ caps,
    const float* __restrict__ W, const float* __restrict__ b1,
    const float* __restrict__ b2, float* __restrict__ C,
    int M, int N, int K)
{
  __shared__ float As[16][68];
  __shared__ float Ws[16][68];
  const int tid = threadIdx.x;
  const int tx = tid & 15, ty = tid >> 4;
  const int m0 = blockIdx.y * 64, n0 = blockIdx.x * 64;
  const int lm = tid >> 2, lk = (tid & 3) * 4;
  const int wk = tid >> 4, wn = (tid & 15) * 4;
  const int r = m0 + lm;
  const float* arow = nullptr;
  if (r < M) {
    int tt = r >> 5, bb = r & 31;
    arow = Emb + (size_t)caps[bb * LCAP + tt] * K;
  }
  float acc[4][4] = {};
  for (int k0 = 0; k0 < K; k0 += 16) {
    float4 av = make_float4(0.f, 0.f, 0.f, 0.f);
    if (arow) av = *(const float4*)&arow[k0 + lk];
    As[lk + 0][lm] = av.x; As[lk + 1][lm] = av.y; As[lk + 2][lm] = av.z; As[lk + 3][lm] = av.w;
    *(float4*)&Ws[wk][wn] = *(const float4*)&W[(size_t)(k0 + wk) * N + n0 + wn];
    __syncthreads();
#pragma unroll
    for (int k = 0; k < 16; ++k) {
      float a_[4], w_[4];
#pragma unroll
      for (int i = 0; i < 4; ++i) a_[i] = As[k][ty * 4 + i];
#pragma unroll
      for (int j = 0; j < 4; ++j) w_[j] = Ws[k][tx * 4 + j];
#pragma unroll
      for (int i = 0; i < 4; ++i)
#pragma unroll
        for (int j = 0; j < 4; ++j) acc[i][j] += a_[i] * w_[j];
    }
    __syncthreads();
  }
#pragma unroll
  for (int i = 0; i < 4; ++i) {
    int m = m0 + ty * 4 + i;
    if (m < M) {
#pragma unroll
      for (int j = 0; j < 4; ++j) {
        int n = n0 + tx * 4 + j;
        C[(size_t)m * N + n] = acc[i][j] + b1[n] + b2[n];
      }
    }
  }
}

__global__ __launch_bounds__(256) void avgk(const float* __restrict__ enc, float* __restrict__ avg)
{
  int idx = blockIdx.x * 256 + threadIdx.x;
  int b = idx >> 11, e = idx & 2047;
  float s = 0.f;
  for (int p = 0; p < NP; ++p) s += enc[(size_t)(b * NP + p) * ENC + e];
  avg[idx] = s * (1.f / 196.f);
}

__device__ __forceinline__ void tile32x64(
    const float* __restrict__ Arows, int lda,
    const float* __restrict__ W, int ldw, int ncol,
    int k_begin, int k_end,
    float (*As)[33], float (*Ws)[68], float acc[2][4])
{
  const int tid = threadIdx.x;
  const int tx = tid & 15, ty = tid >> 4;
  const int lm = tid >> 3, lk = (tid & 7) * 4;
  const int wk = tid >> 4, wn = (tid & 15) * 4;
  for (int k0 = k_begin; k0 < k_end; k0 += 32) {
    float4 av = *(const float4*)&Arows[lm * lda + k0 + lk];
    As[lk + 0][lm] = av.x; As[lk + 1][lm] = av.y; As[lk + 2][lm] = av.z; As[lk + 3][lm] = av.w;
    *(float4*)&Ws[wk][wn]      = *(const float4*)&W[(size_t)(k0 + wk) * ldw + ncol + wn];
    *(float4*)&Ws[wk + 16][wn] = *(const float4*)&W[(size_t)(k0 + wk + 16) * ldw + ncol + wn];
    __syncthreads();
#pragma unroll
    for (int k = 0; k < 32; ++k) {
      float a0 = As[k][ty * 2], a1 = As[k][ty * 2 + 1];
      float4 w = *(const float4*)&Ws[k][tx * 4];
      acc[0][0] += a0 * w.x; acc[0][1] += a0 * w.y; acc[0][2] += a0 * w.z; acc[0][3] += a0 * w.w;
      acc[1][0] += a1 * w.x; acc[1][1] += a1 * w.y; acc[1][2] += a1 * w.z; acc[1][3] += a1 * w.w;
    }
    __syncthreads();
  }
}

__device__ void k1_body(int nb, int s, const float* __restrict__ h,
                        const float* __restrict__ Wd, const float* __restrict__ Wfb,
                        float* __restrict__ P1, float (*As)[33], float (*Ws)[68])
{
  int n0 = nb * 64;
  const float* W; int ldw, ncol;
  if (n0 < 512) { W = Wd; ldw = 512; ncol = n0; }
  else          { W = Wfb; ldw = 2048; ncol = n0 - 512; }
  float acc[2][4] = {};
  tile32x64(h, 512, W, ldw, ncol, s * 128, s * 128 + 128, As, Ws, acc);
  int tx = threadIdx.x & 15, ty = threadIdx.x >> 4;
#pragma unroll
  for (int i = 0; i < 2; ++i)
#pragma unroll
    for (int j = 0; j < 4; ++j)
      P1[s * (32 * 2560) + (ty * 2 + i) * 2560 + n0 + tx * 4 + j] = acc[i][j];
}

__global__ __launch_bounds__(256) void k1_decgate(
    const float* __restrict__ h, const float* __restrict__ Wd,
    const float* __restrict__ Wfb, float* __restrict__ P1)
{
  __shared__ float As[32][33];
  __shared__ float Ws[32][68];
  k1_body(blockIdx.x, blockIdx.y, h, Wd, Wfb, P1, As, Ws);
}

__global__ __launch_bounds__(256) void k2_attn(
    const float* __restrict__ P1, const float* __restrict__ bdec, const float* __restrict__ bfb,
    const float* __restrict__ watt, const float* __restrict__ batt,
    const float* __restrict__ encatt, const float* __restrict__ enc,
    const int* __restrict__ clen, float* __restrict__ outa, float* __restrict__ aweg, int t)
{
  int b = blockIdx.x, tid = threadIdx.x;
  __shared__ float dec_s[512], watt_s[512], al_s[196], red_s[256];
  for (int a = tid; a < 512; a += 256) {
    float v = bdec[a];
#pragma unroll
    for (int s = 0; s < 4; ++s) v += P1[s * (32 * 2560) + b * 2560 + a];
    dec_s[a] = v;
    watt_s[a] = watt[a];
  }
  __syncthreads();
  float e = -1e30f;
  if (tid < NP) {
    const float* row = encatt + (size_t)(b * NP + tid) * 512;
    float acc = 0.f;
    for (int a = 0; a < 512; a += 4) {
      float4 ev = *(const float4*)&row[a];
      acc += fmaxf(ev.x + dec_s[a + 0], 0.f) * watt_s[a + 0];
      acc += fmaxf(ev.y + dec_s[a + 1], 0.f) * watt_s[a + 1];
      acc += fmaxf(ev.z + dec_s[a + 2], 0.f) * watt_s[a + 2];
      acc += fmaxf(ev.w + dec_s[a + 3], 0.f) * watt_s[a + 3];
    }
    e = acc + batt[0];
  }
  red_s[tid] = e;
  __syncthreads();
  for (int w = 128; w > 0; w >>= 1) {
    if (tid < w) red_s[tid] = fmaxf(red_s[tid], red_s[tid + w]);
    __syncthreads();
  }
  float m = red_s[0];
  __syncthreads();
  float ex = (tid < NP) ? expf(e - m) : 0.f;
  red_s[tid] = ex;
  __syncthreads();
  for (int w = 128; w > 0; w >>= 1) {
    if (tid < w) red_s[tid] += red_s[tid + w];
    __syncthreads();
  }
  float inv = 1.f / red_s[0];
  bool act = clen[b] - 1 > t;
  if (tid < NP) {
    float al = ex * inv;
    al_s[tid] = al;
    outa[(size_t)(b * TS + t) * NP + tid] = act ? al : 0.f;
  }
  __syncthreads();
#pragma unroll
  for (int it = 0; it < 2; ++it) {
    int d = (it * 256 + tid) * 4;
    float ax = 0.f, ay = 0.f, az = 0.f, aw = 0.f;
    for (int p = 0; p < NP; ++p) {
      float al = al_s[p];
      float4 ev = *(const float4*)&enc[(size_t)(b * NP + p) * ENC + d];
      ax += al * ev.x; ay += al * ev.y; az += al * ev.z; aw += al * ev.w;
    }
    float gx = bfb[d + 0], gy = bfb[d + 1], gz = bfb[d + 2], gw = bfb[d + 3];
#pragma unroll
    for (int s = 0; s < 4; ++s) {
      const float* p1 = P1 + s * (32 * 2560) + b * 2560 + 512 + d;
      gx += p1[0]; gy += p1[1]; gz += p1[2]; gw += p1[3];
    }
    float4 o;
    o.x = sigm(gx) * ax; o.y = sigm(gy) * ay; o.z = sigm(gz) * az; o.w = sigm(gw) * aw;
    *(float4*)&aweg[b * ENC + d] = o;
  }
}

__global__ __launch_bounds__(256) void k3_g(
    const float* __restrict__ aweg, const float* __restrict__ h,
    const float* __restrict__ Wih, const float* __restrict__ Whh,
    float* __restrict__ P2)
{
  __shared__ float As[32][33];
  __shared__ float Ws[32][68];
  const int n0 = blockIdx.x * 64;
  const int s = blockIdx.y;
  const int tid = threadIdx.x;
  const int tx = tid & 15, ty = tid >> 4;
  const int lm = tid >> 3, lk = (tid & 7) * 4;
  const int wk = tid >> 4, wn = (tid & 15) * 4;
  float acc[2][4] = {};
  for (int k0 = s * 320; k0 < s * 320 + 320; k0 += 32) {
    const float* Ab; int lda, kb; const float* Wb;
    if (k0 < 2048) { Ab = aweg; lda = 2048; kb = k0; Wb = Wih + (size_t)(512 + k0) * 2048; }
    else           { Ab = h;    lda = 512;  kb = k0 - 2048; Wb = Whh + (size_t)(k0 - 2048) * 2048; }
    float4 av = *(const float4*)&Ab[lm * lda + kb + lk];
    As[lk + 0][lm] = av.x; As[lk + 1][lm] = av.y; As[lk + 2][lm] = av.z; As[lk + 3][lm] = av.w;
    *(float4*)&Ws[wk][wn]      = *(const float4*)&Wb[(size_t)wk * 2048 + n0 + wn];
    *(float4*)&Ws[wk + 16][wn] = *(const float4*)&Wb[(size_t)(wk + 16) * 2048 + n0 + wn];
    __syncthreads();
#pragma unroll
    for (int k = 0; k < 32; ++k) {
      float a0 = As[k][ty * 2], a1 = As[k][ty * 2 + 1];
      float4 w = *(const float4*)&Ws[k][tx * 4];
      acc[0][0] += a0 * w.x; acc[0][1] += a0 * w.y; acc[0][2] += a0 * w.z; acc[0][3] += a0 * w.w;
      acc[1][0] += a1 * w.x; acc[1][1] += a1 * w.y; acc[1][2] += a1 * w.z; acc[1][3] += a1 * w.w;
    }
    __syncthreads();
  }
#pragma unroll
  for (int i = 0; i < 2; ++i)
#pragma unroll
    for (int j = 0; j < 4; ++j)
      P2[s * (32 * 2048) + (ty * 2 + i) * 2048 + n0 + tx * 4 + j] = acc[i][j];
}

__global__ __launch_bounds__(256) void k4_lstm(
    const float* __restrict__ P2, const float* __restrict__ embproj,
    const int* __restrict__ clen, float* __restrict__ h, float* __restrict__ c, int t)
{
  int idx = blockIdx.x * 256 + threadIdx.x;
  int b = idx >> 9, d = idx & 511;
  const float* ep = embproj + (size_t)(t * 32 + b) * 2048;
  float i_ = ep[d], f_ = ep[512 + d], g_ = ep[1024 + d], o_ = ep[1536 + d];
#pragma unroll
  for (int s = 0; s < 8; ++s) {
    const float* p2 = P2 + s * (32 * 2048) + b * 2048;
    i_ += p2[d]; f_ += p2[512 + d]; g_ += p2[1024 + d]; o_ += p2[1536 + d];
  }
  float cv = c[idx];
  float cn = sigm(f_) * cv + sigm(i_) * tanhf(g_);
  float hn = sigm(o_) * tanhf(cn);
  if (clen[b] - 1 > t) { h[idx] = hn; c[idx] = cn; }
}

__global__ __launch_bounds__(256) void km_preds_k1(
    const float* __restrict__ h, const float* __restrict__ Wfc, const float* __restrict__ bfc,
    const int* __restrict__ clen, float* __restrict__ outp, int t,
    const float* __restrict__ Wd, const float* __restrict__ Wfb, float* __restrict__ P1,
    int do_k1)
{
  __shared__ float As[32][33];
  __shared__ float Ws[32][68];
  int bid = blockIdx.x;
  if (bid < 500) {
    int n0 = bid * 64;
    float acc[2][4] = {};
    tile32x64(h, 512, Wfc, VOC, n0, 0, 512, As, Ws, acc);
    int tx = threadIdx.x & 15, ty = threadIdx.x >> 4;
#pragma unroll
    for (int i = 0; i < 2; ++i) {
      int b = ty * 2 + i;
      bool act = clen[b] - 1 > t;
#pragma unroll
      for (int j = 0; j < 4; ++j) {
        int n = n0 + tx * 4 + j;
        outp[(size_t)b * (TS * VOC) + (size_t)t * VOC + n] = act ? (acc[i][j] + bfc[n]) : 0.f;
      }
    }
  } else if (do_k1) {
    int i2 = bid - 500;
    k1_body(i2 % 40, i2 / 40, h, Wd, Wfb, P1, As, Ws);
  }
}

// =====================================================================
extern "C" void kernel_launch(void* const* d_in, const int* in_sizes, int n_in,
                              void* d_out, int out_size, void* d_ws, size_t ws_size,
                              hipStream_t stream)
{
  (void)in_sizes; (void)n_in; (void)out_size;
  const float* enc   = (const float*)d_in[0];
  const int*   caps  = (const int*)d_in[1];
  const int*   clen  = (const int*)d_in[2];
  const float* emb   = (const float*)d_in[3];
  const float* W_enc = (const float*)d_in[4];
  const float* b_enc = (const float*)d_in[5];
  const float* W_dec = (const float*)d_in[6];
  const float* b_dec = (const float*)d_in[7];
  const float* w_att = (const float*)d_in[8];
  const float* b_att = (const float*)d_in[9];
  const float* W_ih  = (const float*)d_in[10];
  const float* b_ih  = (const float*)d_in[11];
  const float* W_hh  = (const float*)d_in[12];
  const float* b_hh  = (const float*)d_in[13];
  const float* W_h   = (const float*)d_in[14];
  const float* b_h   = (const float*)d_in[15];
  const float* W_c   = (const float*)d_in[16];
  const float* b_c   = (const float*)d_in[17];
  const float* W_fb  = (const float*)d_in[18];
  const float* b_fb  = (const float*)d_in[19];
  const float* W_fc  = (const float*)d_in[20];
  const float* b_fc  = (const float*)d_in[21];

  float* out_preds = (float*)d_out;
  float* out_alpha = out_preds + (size_t)NB * TS * VOC;

  // ---------- new-path workspace layout (bytes) ----------
  const size_t NEED = 173539328;
  if (ws_size >= NEED) {
    char* p = (char*)d_ws;
    float* encatt   = (float*)p;            p += 12845056;   // 6272*512 f32
    float* embproj  = (float*)p;            p += 10223616;   // 1248*2048 f32
    float* P2buf    = (float*)p;            p += 2097152;    // 8*32*2048 f32
    float* dec_gate = (float*)p;            p += 327680;     // 32*2560 f32
    float* avg      = (float*)p;            p += 262144;     // 32*2048 f32
    float* h0f      = (float*)p;            p += 65536;      // 32*512 f32
    float* cbuf     = (float*)p;            p += 65536;      // 32*512 f32
    ushort_t* h_hi  = (ushort_t*)p;         p += 32768;      // 32*512 bf16
    ushort_t* h_lo  = (ushort_t*)p;         p += 32768;
    ushort_t* aw_hi = (ushort_t*)p;         p += 131072;     // 32*2048
    ushort_t* aw_lo = (ushort_t*)p;         p += 131072;
    ushort_t* e_hi  = (ushort_t*)p;         p += 25690112;   // 6272*2048
    ushort_t* e_lo  = (ushort_t*)p;         p += 25690112;
    ushort_t* We_hi = (ushort_t*)p;         p += 2097152;    // 512 x 2048
    ushort_t* We_lo = (ushort_t*)p;         p += 2097152;
    ushort_t* W1_hi = (ushort_t*)p;         p += 2621440;    // 2560 x 512
    ushort_t* W1_lo = (ushort_t*)p;         p += 2621440;
    ushort_t* W3_hi = (ushort_t*)p;         p += 10485760;   // 2048 x 2560
    ushort_t* W3_lo = (ushort_t*)p;         p += 10485760;
    ushort_t* Wf_hi = (ushort_t*)p;         p += 32768000;   // 32000 x 512
    ushort_t* Wf_lo = (ushort_t*)p;         p += 32768000;

    // prologue
    avgk<<<dim3(256), 256, 0, stream>>>(enc, avg);
    gemm64<<<dim3(8, 1), 256, 0, stream>>>(avg, W_h, b_h, h0f, 32, 512, 2048);
    gemm64<<<dim3(8, 1), 256, 0, stream>>>(avg, W_c, b_c, cbuf, 32, 512, 2048);
    convA<<<dim3(12544), 256, 0, stream>>>(enc, e_hi, e_lo, 3211264);
    convA<<<dim3(16), 256, 0, stream>>>(h0f, h_hi, h_lo, 4096);
    // W_enc [2048][512] -> We_t [512][2048]
    convT<<<dim3(16, 64), 256, 0, stream>>>(W_enc, 512, We_hi, We_lo, 2048);
    // W_dec [512][512] -> W1_t rows 0..511 (ld 512)
    convT<<<dim3(16, 16), 256, 0, stream>>>(W_dec, 512, W1_hi, W1_lo, 512);
    // W_fb [512][2048] -> W1_t rows 512..2559
    convT<<<dim3(64, 16), 256, 0, stream>>>(W_fb, 2048, W1_hi + (size_t)512 * 512,
                                            W1_lo + (size_t)512 * 512, 512);
    // W_ih rows 512..2559 [2048][2048] -> W3_t cols 0..2047 (ld 2560)
    convT<<<dim3(64, 64), 256, 0, stream>>>(W_ih + (size_t)512 * 2048, 2048, W3_hi, W3_lo, 2560);
    // W_hh [512][2048] -> W3_t cols 2048..2559
    convT<<<dim3(64, 16), 256, 0, stream>>>(W_hh, 2048, W3_hi + 2048, W3_lo + 2048, 2560);
    // W_fc [512][32000] -> Wf_t [32000][512]
    convT<<<dim3(1000, 16), 256, 0, stream>>>(W_fc, VOC, Wf_hi, Wf_lo, 512);

    menc_att<<<dim3(4, 196), 256, 0, stream>>>(e_hi, e_lo, We_hi, We_lo, b_enc, encatt);
    gemm_emb<<<dim3(32, 20), 256, 0, stream>>>(emb, caps, W_ih, b_ih, b_hh, embproj, 1248, 2048, 512);
    mk1<<<dim3(20), 256, 0, stream>>>(h_hi, h_lo, W1_hi, W1_lo, dec_gate);

    for (int t = 0; t < TS; ++t) {
      k2_attn2<<<dim3(32, 4), 256, 0, stream>>>(dec_gate, b_dec, b_fb, w_att, b_att,
                                                encatt, enc, clen, out_alpha, aw_hi, aw_lo, t);
      mk3<<<dim3(16, 8), 256, 0, stream>>>(aw_hi, aw_lo, h_hi, h_lo, W3_hi, W3_lo, P2buf);
      k4_lstm2<<<dim3(64), 256, 0, stream>>>(P2buf, embproj, clen, cbuf, h_hi, h_lo, t);
      mkm<<<dim3(270), 256, 0, stream>>>(h_hi, h_lo, Wf_hi, Wf_lo, b_fc, clen, out_preds, t,
                                         W1_hi, W1_lo, dec_gate, (t < TS - 1) ? 1 : 0);
    }
    return;
  }

  // ---------- fallback: old f32 path ----------
  float* ws      = (float*)d_ws;
  float* avg     = ws;
  float* h       = avg + 65536;
  float* c       = h + 16384;
  float* encatt  = c + 16384;
  float* embproj = encatt + 3211264;
  float* P1buf   = embproj + 2555904;
  float* aweg    = P1buf + 327680;
  float* P2buf   = aweg + 65536;

  avgk<<<dim3(256), 256, 0, stream>>>(enc, avg);
  gemm64<<<dim3(8, 1), 256, 0, stream>>>(avg, W_h, b_h, h, 32, 512, 2048);
  gemm64<<<dim3(8, 1), 256, 0, stream>>>(avg, W_c, b_c, c, 32, 512, 2048);
  gemm64<<<dim3(8, 98), 256, 0, stream>>>(enc, W_enc, b_enc, encatt, 6272, 512, 2048);
  gemm_emb<<<dim3(32, 20), 256, 0, stream>>>(emb, caps, W_ih, b_ih, b_hh, embproj, 1248, 2048, 512);
  k1_decgate<<<dim3(40, 4), 256, 0, stream>>>(h, W_dec, W_fb, P1buf);

  for (int t = 0; t < TS; ++t) {
    k2_attn<<<dim3(32), 256, 0, stream>>>(P1buf, b_dec, b_fb, w_att, b_att,
                                          encatt, enc, clen, out_alpha, aweg, t);
    k3_g<<<dim3(32, 8), 256, 0, stream>>>(aweg, h, W_ih, W_hh, P2buf);
    k4_lstm<<<dim3(64), 256, 0, stream>>>(P2buf, embproj, clen, h, c, t);
    km_preds_k1<<<dim3(660), 256, 0, stream>>>(h, W_fc, b_fc, clen, out_preds, t,
                                               W_dec, W_fb, P1buf, (t < TS - 1) ? 1 : 0);
  }
}

// Round 4
// 3743.681 us; speedup vs baseline: 1.1022x; 1.0889x over previous
//
#include <hip/hip_runtime.h>
#include <math.h>

#define NB 32
#define NP 196
#define ENC 2048
#define VOC 32000
#define LCAP 40
#define TS 39

typedef unsigned int uint_t;
typedef unsigned short ushort_t;

__device__ __forceinline__ float sigm(float x) { return 1.f / (1.f + expf(-x)); }

// ---------- bf16 helpers (RNE) ----------
__device__ __forceinline__ ushort_t f2bf(float f) {
  uint_t u = __float_as_uint(f);
  u = (u + 0x7FFFu + ((u >> 16) & 1u)) >> 16;
  return (ushort_t)u;
}
__device__ __forceinline__ float bf2f(ushort_t s) { return __uint_as_float(((uint_t)s) << 16); }

typedef __attribute__((ext_vector_type(8))) short bf8v;
typedef __attribute__((ext_vector_type(16))) float f16v;

__device__ __forceinline__ f16v MFMA(bf8v a, bf8v b, f16v c) {
  return __builtin_amdgcn_mfma_f32_32x32x16_bf16(a, b, c, 0, 0, 0);
}

// =====================================================================
// Pipelined MFMA core: one wave -> C[32 x 32] over [kbeg,kend), split-bf16.
// Depth-4 rotate-in-place register prefetch (4 slots x {ah,al,bh,bl}).
// (kend-kbeg) must be a multiple of 64.
// A: [32][ldA] bf16 hi/lo row-major.  W: [N][ldW] hi/lo (row n = out col).
// =====================================================================
__device__ __forceinline__ void mfma_pipe(
    const ushort_t* __restrict__ Ahi, const ushort_t* __restrict__ Alo, int ldA,
    const ushort_t* __restrict__ Whi, const ushort_t* __restrict__ Wlo, int ldW,
    int col0, int kbeg, int kend, f16v& acc)
{
  const int lane = threadIdx.x & 63;
  const int r = lane & 31, g = lane >> 5;
  const ushort_t* pa_h = Ahi + (size_t)r * ldA + g * 8 + kbeg;
  const ushort_t* pa_l = Alo + (size_t)r * ldA + g * 8 + kbeg;
  const ushort_t* pb_h = Whi + (size_t)(col0 + r) * ldW + g * 8 + kbeg;
  const ushort_t* pb_l = Wlo + (size_t)(col0 + r) * ldW + g * 8 + kbeg;
  const int nch = (kend - kbeg) >> 6;
  bf8v ah0 = *(const bf8v*)(pa_h +  0), al0 = *(const bf8v*)(pa_l +  0);
  bf8v bh0 = *(const bf8v*)(pb_h +  0), bl0 = *(const bf8v*)(pb_l +  0);
  bf8v ah1 = *(const bf8v*)(pa_h + 16), al1 = *(const bf8v*)(pa_l + 16);
  bf8v bh1 = *(const bf8v*)(pb_h + 16), bl1 = *(const bf8v*)(pb_l + 16);
  bf8v ah2 = *(const bf8v*)(pa_h + 32), al2 = *(const bf8v*)(pa_l + 32);
  bf8v bh2 = *(const bf8v*)(pb_h + 32), bl2 = *(const bf8v*)(pb_l + 32);
  bf8v ah3 = *(const bf8v*)(pa_h + 48), al3 = *(const bf8v*)(pa_l + 48);
  bf8v bh3 = *(const bf8v*)(pb_h + 48), bl3 = *(const bf8v*)(pb_l + 48);
  for (int c = 0; c < nch; ++c) {
    const int kn = (c + 1) << 6;
    const bool more = (c + 1 < nch);
    acc = MFMA(ah0, bh0, acc); acc = MFMA(ah0, bl0, acc); acc = MFMA(al0, bh0, acc);
    if (more) {
      ah0 = *(const bf8v*)(pa_h + kn +  0); al0 = *(const bf8v*)(pa_l + kn +  0);
      bh0 = *(const bf8v*)(pb_h + kn +  0); bl0 = *(const bf8v*)(pb_l + kn +  0);
    }
    acc = MFMA(ah1, bh1, acc); acc = MFMA(ah1, bl1, acc); acc = MFMA(al1, bh1, acc);
    if (more) {
      ah1 = *(const bf8v*)(pa_h + kn + 16); al1 = *(const bf8v*)(pa_l + kn + 16);
      bh1 = *(const bf8v*)(pb_h + kn + 16); bl1 = *(const bf8v*)(pb_l + kn + 16);
    }
    acc = MFMA(ah2, bh2, acc); acc = MFMA(ah2, bl2, acc); acc = MFMA(al2, bh2, acc);
    if (more) {
      ah2 = *(const bf8v*)(pa_h + kn + 32); al2 = *(const bf8v*)(pa_l + kn + 32);
      bh2 = *(const bf8v*)(pb_h + kn + 32); bl2 = *(const bf8v*)(pb_l + kn + 32);
    }
    acc = MFMA(ah3, bh3, acc); acc = MFMA(ah3, bl3, acc); acc = MFMA(al3, bh3, acc);
    if (more) {
      ah3 = *(const bf8v*)(pa_h + kn + 48); al3 = *(const bf8v*)(pa_l + kn + 48);
      bh3 = *(const bf8v*)(pb_h + kn + 48); bl3 = *(const bf8v*)(pb_l + kn + 48);
    }
  }
}

// C/D mapping (HW-verified): col = lane&31, row = (reg&3)+8*(reg>>2)+4*(lane>>5)
#define CD_ROW(rr, g) (((rr) & 3) + 8 * ((rr) >> 2) + 4 * (g))

// ---------------- enc_att: encatt = enc @ W_enc + b_enc ----------------
__global__ __launch_bounds__(256) void menc_att(
    const ushort_t* __restrict__ Ahi, const ushort_t* __restrict__ Alo,
    const ushort_t* __restrict__ Whi, const ushort_t* __restrict__ Wlo,
    const float* __restrict__ benc, float* __restrict__ encatt)
{
  int w = threadIdx.x >> 6;
  int m0 = blockIdx.y * 32;
  int col0 = blockIdx.x * 128 + w * 32;
  f16v acc = (f16v)(0.0f);
  mfma_pipe(Ahi + (size_t)m0 * ENC, Alo + (size_t)m0 * ENC, ENC,
            Whi, Wlo, ENC, col0, 0, ENC, acc);
  int lane = threadIdx.x & 63, r = lane & 31, g = lane >> 5;
  int n = col0 + r;
  float bn = benc[n];
#pragma unroll
  for (int rr = 0; rr < 16; ++rr)
    encatt[(size_t)(m0 + CD_ROW(rr, g)) * 512 + n] = acc[rr] + bn;
}

// ---------------- k1: dec_gate = h @ [W_dec | W_fb] ----------------
__global__ __launch_bounds__(256) void mk1(
    const ushort_t* __restrict__ hhi, const ushort_t* __restrict__ hlo,
    const ushort_t* __restrict__ W1hi, const ushort_t* __restrict__ W1lo,
    float* __restrict__ dec_gate)
{
  int w = threadIdx.x >> 6;
  int col0 = blockIdx.x * 128 + w * 32;
  f16v acc = (f16v)(0.0f);
  mfma_pipe(hhi, hlo, 512, W1hi, W1lo, 512, col0, 0, 512, acc);
  int lane = threadIdx.x & 63, r = lane & 31, g = lane >> 5;
  int n = col0 + r;
#pragma unroll
  for (int rr = 0; rr < 16; ++rr)
    dec_gate[CD_ROW(rr, g) * 2560 + n] = acc[rr];
}

// ---------------- k3: P2[s] = partial of x(=[aweg|h]) @ W3 ----------------
__global__ __launch_bounds__(256) void mk3(
    const ushort_t* __restrict__ xhi, const ushort_t* __restrict__ xlo,
    const ushort_t* __restrict__ W3hi, const ushort_t* __restrict__ W3lo,
    float* __restrict__ P2)
{
  int w = threadIdx.x >> 6;
  int col0 = blockIdx.x * 128 + w * 32;
  int s = blockIdx.y;
  f16v acc = (f16v)(0.0f);
  mfma_pipe(xhi, xlo, 2560, W3hi, W3lo, 2560, col0, s * 320, s * 320 + 320, acc);
  int lane = threadIdx.x & 63, r = lane & 31, g = lane >> 5;
  int n = col0 + r;
#pragma unroll
  for (int rr = 0; rr < 16; ++rr)
    P2[(size_t)s * (32 * 2048) + CD_ROW(rr, g) * 2048 + n] = acc[rr];
}

// ---------------- km: preds(t) [0..249] + k1(t+1) [250..269] ----------------
__global__ __launch_bounds__(256) void mkm(
    const ushort_t* __restrict__ hhi, const ushort_t* __restrict__ hlo,
    const ushort_t* __restrict__ Wfchi, const ushort_t* __restrict__ Wfclo,
    const float* __restrict__ bfc, const int* __restrict__ clen,
    float* __restrict__ outp, int t,
    const ushort_t* __restrict__ W1hi, const ushort_t* __restrict__ W1lo,
    float* __restrict__ dec_gate, int do_k1)
{
  int bid = blockIdx.x;
  int w = threadIdx.x >> 6;
  int lane = threadIdx.x & 63, r = lane & 31, g = lane >> 5;
  if (bid < 250) {
    int col0 = bid * 128 + w * 32;
    f16v acc = (f16v)(0.0f);
    mfma_pipe(hhi, hlo, 512, Wfchi, Wfclo, 512, col0, 0, 512, acc);
    int n = col0 + r;
    float bn = bfc[n];
#pragma unroll
    for (int rr = 0; rr < 16; ++rr) {
      int b = CD_ROW(rr, g);
      bool act = clen[b] - 1 > t;
      outp[(size_t)b * (TS * VOC) + (size_t)t * VOC + n] = act ? (acc[rr] + bn) : 0.f;
    }
  } else if (do_k1) {
    int col0 = (bid - 250) * 128 + w * 32;
    f16v acc = (f16v)(0.0f);
    mfma_pipe(hhi, hlo, 512, W1hi, W1lo, 512, col0, 0, 512, acc);
    int n = col0 + r;
#pragma unroll
    for (int rr = 0; rr < 16; ++rr)
      dec_gate[CD_ROW(rr, g) * 2560 + n] = acc[rr];
  }
}

// ---------------- conversions ----------------
__global__ __launch_bounds__(256) void convA(
    const float* __restrict__ src, ushort_t* __restrict__ dhi,
    ushort_t* __restrict__ dlo, int n4)
{
  int i = blockIdx.x * 256 + threadIdx.x;
  if (i >= n4) return;
  float4 v = *(const float4*)&src[(size_t)i * 4];
  ushort4 hi, lo;
  hi.x = f2bf(v.x); lo.x = f2bf(v.x - bf2f(hi.x));
  hi.y = f2bf(v.y); lo.y = f2bf(v.y - bf2f(hi.y));
  hi.z = f2bf(v.z); lo.z = f2bf(v.z - bf2f(hi.z));
  hi.w = f2bf(v.w); lo.w = f2bf(v.w - bf2f(hi.w));
  *(ushort4*)&dhi[(size_t)i * 4] = hi;
  *(ushort4*)&dlo[(size_t)i * 4] = lo;
}

// transpose-convert: src [K][srcN] f32 -> dst [n][k] bf16 hi/lo (ld = dld)
__global__ __launch_bounds__(256) void convT(
    const float* __restrict__ src, int srcN,
    ushort_t* __restrict__ dhi, ushort_t* __restrict__ dlo, int dld)
{
  __shared__ float t_s[32][36];
  int n0 = blockIdx.x * 32, k0 = blockIdx.y * 32;
  int r = threadIdx.x >> 3, c4 = (threadIdx.x & 7) * 4;
  float4 v = *(const float4*)&src[(size_t)(k0 + r) * srcN + n0 + c4];
  t_s[r][c4 + 0] = v.x; t_s[r][c4 + 1] = v.y; t_s[r][c4 + 2] = v.z; t_s[r][c4 + 3] = v.w;
  __syncthreads();
  float f0 = t_s[c4 + 0][r], f1 = t_s[c4 + 1][r], f2 = t_s[c4 + 2][r], f3 = t_s[c4 + 3][r];
  ushort4 hi, lo;
  hi.x = f2bf(f0); lo.x = f2bf(f0 - bf2f(hi.x));
  hi.y = f2bf(f1); lo.y = f2bf(f1 - bf2f(hi.y));
  hi.z = f2bf(f2); lo.z = f2bf(f2 - bf2f(hi.z));
  hi.w = f2bf(f3); lo.w = f2bf(f3 - bf2f(hi.w));
  *(ushort4*)&dhi[(size_t)(n0 + r) * dld + k0 + c4] = hi;
  *(ushort4*)&dlo[(size_t)(n0 + r) * dld + k0 + c4] = lo;
}

// ---------------- avg over P ----------------
__global__ __launch_bounds__(256) void avgk(const float* __restrict__ enc, float* __restrict__ avg)
{
  int idx = blockIdx.x * 256 + threadIdx.x;   // 32*2048
  int b = idx >> 11, e = idx & 2047;
  float s = 0.f;
  for (int p = 0; p < NP; ++p) s += enc[(size_t)(b * NP + p) * ENC + e];
  avg[idx] = s * (1.f / 196.f);
}

// ---------------- generic 64x64 f32 GEMM (prologue only) ----------------
__global__ __launch_bounds__(256) void gemm64(
    const float* __restrict__ A, const float* __restrict__ W,
    const float* __restrict__ bias, float* __restrict__ C,
    int M, int N, int K)
{
  __shared__ float As[16][68];
  __shared__ float Ws[16][68];
  const int tid = threadIdx.x;
  const int tx = tid & 15, ty = tid >> 4;
  const int m0 = blockIdx.y * 64, n0 = blockIdx.x * 64;
  const int lm = tid >> 2, lk = (tid & 3) * 4;
  const int wk = tid >> 4, wn = (tid & 15) * 4;
  float acc[4][4] = {};
  for (int k0 = 0; k0 < K; k0 += 16) {
    float4 av = make_float4(0.f, 0.f, 0.f, 0.f);
    if (m0 + lm < M) av = *(const float4*)&A[(size_t)(m0 + lm) * K + k0 + lk];
    As[lk + 0][lm] = av.x; As[lk + 1][lm] = av.y; As[lk + 2][lm] = av.z; As[lk + 3][lm] = av.w;
    *(float4*)&Ws[wk][wn] = *(const float4*)&W[(size_t)(k0 + wk) * N + n0 + wn];
    __syncthreads();
#pragma unroll
    for (int k = 0; k < 16; ++k) {
      float a_[4], w_[4];
#pragma unroll
      for (int i = 0; i < 4; ++i) a_[i] = As[k][ty * 4 + i];
#pragma unroll
      for (int j = 0; j < 4; ++j) w_[j] = Ws[k][tx * 4 + j];
#pragma unroll
      for (int i = 0; i < 4; ++i)
#pragma unroll
        for (int j = 0; j < 4; ++j) acc[i][j] += a_[i] * w_[j];
    }
    __syncthreads();
  }
#pragma unroll
  for (int i = 0; i < 4; ++i) {
    int m = m0 + ty * 4 + i;
    if (m < M) {
#pragma unroll
      for (int j = 0; j < 4; ++j) {
        int n = n0 + tx * 4 + j;
        C[(size_t)m * N + n] = acc[i][j] + (bias ? bias[n] : 0.f);
      }
    }
  }
}

// ---------- embedding-gathered GEMM (prologue) ----------
__global__ __launch_bounds__(256) void gemm_emb(
    const float* __restrict__ Emb, const int* __restrict__ caps,
    const float* __restrict__ W, const float* __restrict__ b1,
    const float* __restrict__ b2, float* __restrict__ C,
    int M, int N, int K)
{
  __shared__ float As[16][68];
  __shared__ float Ws[16][68];
  const int tid = threadIdx.x;
  const int tx = tid & 15, ty = tid >> 4;
  const int m0 = blockIdx.y * 64, n0 = blockIdx.x * 64;
  const int lm = tid >> 2, lk = (tid & 3) * 4;
  const int wk = tid >> 4, wn = (tid & 15) * 4;
  const int r = m0 + lm;
  const float* arow = nullptr;
  if (r < M) {
    int tt = r >> 5, bb = r & 31;  // row = t*32 + b
    arow = Emb + (size_t)caps[bb * LCAP + tt] * K;
  }
  float acc[4][4] = {};
  for (int k0 = 0; k0 < K; k0 += 16) {
    float4 av = make_float4(0.f, 0.f, 0.f, 0.f);
    if (arow) av = *(const float4*)&arow[k0 + lk];
    As[lk + 0][lm] = av.x; As[lk + 1][lm] = av.y; As[lk + 2][lm] = av.z; As[lk + 3][lm] = av.w;
    *(float4*)&Ws[wk][wn] = *(const float4*)&W[(size_t)(k0 + wk) * N + n0 + wn];
    __syncthreads();
#pragma unroll
    for (int k = 0; k < 16; ++k) {
      float a_[4], w_[4];
#pragma unroll
      for (int i = 0; i < 4; ++i) a_[i] = As[k][ty * 4 + i];
#pragma unroll
      for (int j = 0; j < 4; ++j) w_[j] = Ws[k][tx * 4 + j];
#pragma unroll
      for (int i = 0; i < 4; ++i)
#pragma unroll
        for (int j = 0; j < 4; ++j) acc[i][j] += a_[i] * w_[j];
    }
    __syncthreads();
  }
#pragma unroll
  for (int i = 0; i < 4; ++i) {
    int m = m0 + ty * 4 + i;
    if (m < M) {
#pragma unroll
      for (int j = 0; j < 4; ++j) {
        int n = n0 + tx * 4 + j;
        C[(size_t)m * N + n] = acc[i][j] + b1[n] + b2[n];
      }
    }
  }
}

// ---------------- h split: h0f -> hb hi/lo + x h-cols ----------------
__global__ __launch_bounds__(256) void hsplit0(
    const float* __restrict__ h0f, ushort_t* __restrict__ hbhi, ushort_t* __restrict__ hblo,
    ushort_t* __restrict__ xhi, ushort_t* __restrict__ xlo)
{
  int idx = blockIdx.x * 256 + threadIdx.x;  // 32*512
  int b = idx >> 9, d = idx & 511;
  float v = h0f[idx];
  ushort_t hh = f2bf(v), hl = f2bf(v - bf2f(hh));
  hbhi[idx] = hh; hblo[idx] = hl;
  xhi[b * 2560 + 2048 + d] = hh;
  xlo[b * 2560 + 2048 + d] = hl;
}

// ---------------- k2a: e + softmax per batch row ----------------
__global__ __launch_bounds__(256) void k2a_soft(
    const float* __restrict__ dec_gate, const float* __restrict__ bdec,
    const float* __restrict__ watt, const float* __restrict__ batt,
    const float* __restrict__ encatt, const int* __restrict__ clen,
    float* __restrict__ outa, float* __restrict__ al_ws, int t)
{
  int b = blockIdx.x, tid = threadIdx.x;
  __shared__ float dec_s[512], watt_s[512], red_s[256];
  for (int a = tid; a < 512; a += 256) {
    dec_s[a] = dec_gate[b * 2560 + a] + bdec[a];
    watt_s[a] = watt[a];
  }
  __syncthreads();
  float e = -1e30f;
  if (tid < NP) {
    const float* row = encatt + (size_t)(b * NP + tid) * 512;
    float acc = 0.f;
    for (int a = 0; a < 512; a += 4) {
      float4 ev = *(const float4*)&row[a];
      acc += fmaxf(ev.x + dec_s[a + 0], 0.f) * watt_s[a + 0];
      acc += fmaxf(ev.y + dec_s[a + 1], 0.f) * watt_s[a + 1];
      acc += fmaxf(ev.z + dec_s[a + 2], 0.f) * watt_s[a + 2];
      acc += fmaxf(ev.w + dec_s[a + 3], 0.f) * watt_s[a + 3];
    }
    e = acc + batt[0];
  }
  red_s[tid] = e;
  __syncthreads();
  for (int w = 128; w > 0; w >>= 1) {
    if (tid < w) red_s[tid] = fmaxf(red_s[tid], red_s[tid + w]);
    __syncthreads();
  }
  float m = red_s[0];
  __syncthreads();
  float ex = (tid < NP) ? expf(e - m) : 0.f;
  red_s[tid] = ex;
  __syncthreads();
  for (int w = 128; w > 0; w >>= 1) {
    if (tid < w) red_s[tid] += red_s[tid + w];
    __syncthreads();
  }
  float inv = 1.f / red_s[0];
  if (tid < NP) {
    float al = ex * inv;
    al_ws[b * NP + tid] = al;
    bool act = clen[b] - 1 > t;
    outa[(size_t)(b * TS + t) * NP + tid] = act ? al : 0.f;
  }
}

// ---------------- k2b: awe + gate -> x cols 0..2047 (grid 32 x 8) ----------------
__global__ __launch_bounds__(256) void k2b_awe(
    const float* __restrict__ al_ws, const float* __restrict__ dec_gate,
    const float* __restrict__ bfb, const float* __restrict__ enc,
    ushort_t* __restrict__ xhi, ushort_t* __restrict__ xlo)
{
  int b = blockIdx.x, ds = blockIdx.y, tid = threadIdx.x;
  __shared__ float al_s[196];
  __shared__ float part[4][64][4];
  if (tid < NP) al_s[tid] = al_ws[b * NP + tid];
  __syncthreads();
  int q = tid & 63, sp = tid >> 6;
  int d = ds * 256 + q * 4;
  float ax = 0.f, ay = 0.f, az = 0.f, aw = 0.f;
  int p0 = sp * 49;
#pragma unroll 7
  for (int p = p0; p < p0 + 49; ++p) {
    float al = al_s[p];
    float4 ev = *(const float4*)&enc[(size_t)(b * NP + p) * ENC + d];
    ax += al * ev.x; ay += al * ev.y; az += al * ev.z; aw += al * ev.w;
  }
  part[sp][q][0] = ax; part[sp][q][1] = ay; part[sp][q][2] = az; part[sp][q][3] = aw;
  __syncthreads();
  if (sp == 0) {
    ax = part[0][q][0] + part[1][q][0] + part[2][q][0] + part[3][q][0];
    ay = part[0][q][1] + part[1][q][1] + part[2][q][1] + part[3][q][1];
    az = part[0][q][2] + part[1][q][2] + part[2][q][2] + part[3][q][2];
    aw = part[0][q][3] + part[1][q][3] + part[2][q][3] + part[3][q][3];
    float4 gg = *(const float4*)&dec_gate[b * 2560 + 512 + d];
    float4 bb = *(const float4*)&bfb[d];
    float v0 = sigm(gg.x + bb.x) * ax;
    float v1 = sigm(gg.y + bb.y) * ay;
    float v2 = sigm(gg.z + bb.z) * az;
    float v3 = sigm(gg.w + bb.w) * aw;
    ushort4 hi, lo;
    hi.x = f2bf(v0); lo.x = f2bf(v0 - bf2f(hi.x));
    hi.y = f2bf(v1); lo.y = f2bf(v1 - bf2f(hi.y));
    hi.z = f2bf(v2); lo.z = f2bf(v2 - bf2f(hi.z));
    hi.w = f2bf(v3); lo.w = f2bf(v3 - bf2f(hi.w));
    *(ushort4*)&xhi[b * 2560 + d] = hi;
    *(ushort4*)&xlo[b * 2560 + d] = lo;
  }
}

// ---------------- k4: LSTM pointwise + state update ----------------
__global__ __launch_bounds__(256) void k4_lstm3(
    const float* __restrict__ P2, const float* __restrict__ embproj,
    const int* __restrict__ clen, float* __restrict__ c,
    ushort_t* __restrict__ hbhi, ushort_t* __restrict__ hblo,
    ushort_t* __restrict__ xhi, ushort_t* __restrict__ xlo, int t)
{
  int idx = blockIdx.x * 256 + threadIdx.x;  // 32*512
  int b = idx >> 9, d = idx & 511;
  const float* ep = embproj + (size_t)(t * 32 + b) * 2048;
  float i_ = ep[d], f_ = ep[512 + d], g_ = ep[1024 + d], o_ = ep[1536 + d];
#pragma unroll
  for (int s = 0; s < 8; ++s) {
    const float* p2 = P2 + (size_t)s * (32 * 2048) + b * 2048;
    i_ += p2[d]; f_ += p2[512 + d]; g_ += p2[1024 + d]; o_ += p2[1536 + d];
  }
  float cv = c[idx];
  float cn = sigm(f_) * cv + sigm(i_) * tanhf(g_);
  float hn = sigm(o_) * tanhf(cn);
  if (clen[b] - 1 > t) {
    c[idx] = cn;
    ushort_t hh = f2bf(hn), hl = f2bf(hn - bf2f(hh));
    hbhi[idx] = hh; hblo[idx] = hl;
    xhi[b * 2560 + 2048 + d] = hh;
    xlo[b * 2560 + 2048 + d] = hl;
  }
}

// =====================================================================
extern "C" void kernel_launch(void* const* d_in, const int* in_sizes, int n_in,
                              void* d_out, int out_size, void* d_ws, size_t ws_size,
                              hipStream_t stream)
{
  (void)in_sizes; (void)n_in; (void)out_size; (void)ws_size;
  const float* enc   = (const float*)d_in[0];
  const int*   caps  = (const int*)d_in[1];
  const int*   clen  = (const int*)d_in[2];
  const float* emb   = (const float*)d_in[3];
  const float* W_enc = (const float*)d_in[4];
  const float* b_enc = (const float*)d_in[5];
  const float* W_dec = (const float*)d_in[6];
  const float* b_dec = (const float*)d_in[7];
  const float* w_att = (const float*)d_in[8];
  const float* b_att = (const float*)d_in[9];
  const float* W_ih  = (const float*)d_in[10];
  const float* b_ih  = (const float*)d_in[11];
  const float* W_hh  = (const float*)d_in[12];
  const float* b_hh  = (const float*)d_in[13];
  const float* W_h   = (const float*)d_in[14];
  const float* b_h   = (const float*)d_in[15];
  const float* W_c   = (const float*)d_in[16];
  const float* b_c   = (const float*)d_in[17];
  const float* W_fb  = (const float*)d_in[18];
  const float* b_fb  = (const float*)d_in[19];
  const float* W_fc  = (const float*)d_in[20];
  const float* b_fc  = (const float*)d_in[21];

  float* out_preds = (float*)d_out;
  float* out_alpha = out_preds + (size_t)NB * TS * VOC;

  // ---------- workspace layout (total = 173,539,328 bytes, proven to fit) ----------
  char* p = (char*)d_ws;
  float* encatt   = (float*)p;            p += 12845056;   // 6272*512 f32
  float* embproj  = (float*)p;            p += 10223616;   // 1248*2048 f32
  float* P2buf    = (float*)p;            p += 2097152;    // 8*32*2048 f32
  float* dec_gate = (float*)p;            p += 327680;     // 32*2560 f32
  // region A (262,144 B): avg (prologue-only) overlapped by x_lo (loop)
  float* avg      = (float*)p;
  ushort_t* x_lo  = (ushort_t*)p;         p += 262144;
  float* h0f      = (float*)p;            p += 65536;      // 32*512 f32
  float* cbuf     = (float*)p;            p += 65536;      // 32*512 f32
  // region B (262,144 B): al_ws + hb_hi + hb_lo + x_hi
  float* al_ws    = (float*)p;            p += 25088;      // 32*196 f32
  ushort_t* hb_hi = (ushort_t*)p;         p += 32768;      // 32*512 bf16
  ushort_t* hb_lo = (ushort_t*)p;         p += 32768;
  ushort_t* x_hi  = (ushort_t*)p;         p += 163840;     // 32*2560 bf16
  p += 262144 - 25088 - 32768 - 32768 - 163840;            // pad region B to old size
  ushort_t* e_hi  = (ushort_t*)p;         p += 25690112;   // 6272*2048
  ushort_t* e_lo  = (ushort_t*)p;         p += 25690112;
  ushort_t* We_hi = (ushort_t*)p;         p += 2097152;    // 512 x 2048
  ushort_t* We_lo = (ushort_t*)p;         p += 2097152;
  ushort_t* W1_hi = (ushort_t*)p;         p += 2621440;    // 2560 x 512
  ushort_t* W1_lo = (ushort_t*)p;         p += 2621440;
  ushort_t* W3_hi = (ushort_t*)p;         p += 10485760;   // 2048 x 2560
  ushort_t* W3_lo = (ushort_t*)p;         p += 10485760;
  ushort_t* Wf_hi = (ushort_t*)p;         p += 32768000;   // 32000 x 512
  ushort_t* Wf_lo = (ushort_t*)p;         p += 32768000;

  // ---------------- prologue ----------------
  avgk<<<dim3(256), 256, 0, stream>>>(enc, avg);
  gemm64<<<dim3(8, 1), 256, 0, stream>>>(avg, W_h, b_h, h0f, 32, 512, 2048);
  gemm64<<<dim3(8, 1), 256, 0, stream>>>(avg, W_c, b_c, cbuf, 32, 512, 2048);
  convA<<<dim3(12544), 256, 0, stream>>>(enc, e_hi, e_lo, 3211264);
  convT<<<dim3(16, 64), 256, 0, stream>>>(W_enc, 512, We_hi, We_lo, 2048);
  convT<<<dim3(16, 16), 256, 0, stream>>>(W_dec, 512, W1_hi, W1_lo, 512);
  convT<<<dim3(64, 16), 256, 0, stream>>>(W_fb, 2048, W1_hi + (size_t)512 * 512,
                                          W1_lo + (size_t)512 * 512, 512);
  convT<<<dim3(64, 64), 256, 0, stream>>>(W_ih + (size_t)512 * 2048, 2048, W3_hi, W3_lo, 2560);
  convT<<<dim3(64, 16), 256, 0, stream>>>(W_hh, 2048, W3_hi + 2048, W3_lo + 2048, 2560);
  convT<<<dim3(1000, 16), 256, 0, stream>>>(W_fc, VOC, Wf_hi, Wf_lo, 512);

  menc_att<<<dim3(4, 196), 256, 0, stream>>>(e_hi, e_lo, We_hi, We_lo, b_enc, encatt);
  gemm_emb<<<dim3(32, 20), 256, 0, stream>>>(emb, caps, W_ih, b_ih, b_hh, embproj, 1248, 2048, 512);
  hsplit0<<<dim3(64), 256, 0, stream>>>(h0f, hb_hi, hb_lo, x_hi, x_lo);  // after avg reads done
  mk1<<<dim3(20), 256, 0, stream>>>(hb_hi, hb_lo, W1_hi, W1_lo, dec_gate);

  // ---------------- decode loop ----------------
  for (int t = 0; t < TS; ++t) {
    k2a_soft<<<dim3(32), 256, 0, stream>>>(dec_gate, b_dec, w_att, b_att,
                                           encatt, clen, out_alpha, al_ws, t);
    k2b_awe<<<dim3(32, 8), 256, 0, stream>>>(al_ws, dec_gate, b_fb, enc, x_hi, x_lo);
    mk3<<<dim3(16, 8), 256, 0, stream>>>(x_hi, x_lo, W3_hi, W3_lo, P2buf);
    k4_lstm3<<<dim3(64), 256, 0, stream>>>(P2buf, embproj, clen, cbuf,
                                           hb_hi, hb_lo, x_hi, x_lo, t);
    mkm<<<dim3(270), 256, 0, stream>>>(hb_hi, hb_lo, Wf_hi, Wf_lo, b_fc, clen, out_preds, t,
                                       W1_hi, W1_lo, dec_gate, (t < TS - 1) ? 1 : 0);
  }
}

// Round 5
// 2776.726 us; speedup vs baseline: 1.4861x; 1.3482x over previous
//
#include <hip/hip_runtime.h>
#include <math.h>

#define NB 32
#define NP 196
#define ENC 2048
#define VOC 32000
#define LCAP 40
#define TS 39

typedef unsigned int uint_t;
typedef unsigned short ushort_t;

__device__ __forceinline__ float sigm(float x) { return 1.f / (1.f + expf(-x)); }

// ---------- bf16 helpers (RNE) ----------
__device__ __forceinline__ ushort_t f2bf(float f) {
  uint_t u = __float_as_uint(f);
  u = (u + 0x7FFFu + ((u >> 16) & 1u)) >> 16;
  return (ushort_t)u;
}
__device__ __forceinline__ float bf2f(ushort_t s) { return __uint_as_float(((uint_t)s) << 16); }

typedef __attribute__((ext_vector_type(8))) short bf8v;
typedef __attribute__((ext_vector_type(16))) float f16v;
typedef __attribute__((ext_vector_type(4))) float f4v;

__device__ __forceinline__ f16v MFMA(bf8v a, bf8v b, f16v c) {
  return __builtin_amdgcn_mfma_f32_32x32x16_bf16(a, b, c, 0, 0, 0);
}

// =====================================================================
// FRAGMENT LAYOUT: matrix stored as [tile][k_chunk][lane][8] ushorts.
//   A-frag: lane l -> row r=l&31, k = kc*16 + (l>>5)*8 + e
//   B-frag: lane l -> col c=l&31, same k mapping (W^T tiles of 32 cols)
// One wave fragment load = 64 lanes x 16B CONTIGUOUS (1KB) -> 1 transaction
// burst instead of a 32-line gather. Chunk stride = 512 ushorts.
// =====================================================================

// Pipelined MFMA core on frag-layout streams. nquad = (#chunks)/4.
// Pointers pre-offset by +lane*8.
__device__ __forceinline__ void mfma_pipe_frag(
    const ushort_t* __restrict__ pa_h, const ushort_t* __restrict__ pa_l,
    const ushort_t* __restrict__ pb_h, const ushort_t* __restrict__ pb_l,
    int nquad, f16v& acc)
{
  bf8v ah0 = *(const bf8v*)(pa_h +    0), al0 = *(const bf8v*)(pa_l +    0);
  bf8v bh0 = *(const bf8v*)(pb_h +    0), bl0 = *(const bf8v*)(pb_l +    0);
  bf8v ah1 = *(const bf8v*)(pa_h +  512), al1 = *(const bf8v*)(pa_l +  512);
  bf8v bh1 = *(const bf8v*)(pb_h +  512), bl1 = *(const bf8v*)(pb_l +  512);
  bf8v ah2 = *(const bf8v*)(pa_h + 1024), al2 = *(const bf8v*)(pa_l + 1024);
  bf8v bh2 = *(const bf8v*)(pb_h + 1024), bl2 = *(const bf8v*)(pb_l + 1024);
  bf8v ah3 = *(const bf8v*)(pa_h + 1536), al3 = *(const bf8v*)(pa_l + 1536);
  bf8v bh3 = *(const bf8v*)(pb_h + 1536), bl3 = *(const bf8v*)(pb_l + 1536);
  for (int q = 0; q < nquad; ++q) {
    const size_t nk = (size_t)(q + 1) * 2048;
    const bool more = (q + 1 < nquad);
    acc = MFMA(ah0, bh0, acc); acc = MFMA(ah0, bl0, acc); acc = MFMA(al0, bh0, acc);
    if (more) {
      ah0 = *(const bf8v*)(pa_h + nk +    0); al0 = *(const bf8v*)(pa_l + nk +    0);
      bh0 = *(const bf8v*)(pb_h + nk +    0); bl0 = *(const bf8v*)(pb_l + nk +    0);
    }
    acc = MFMA(ah1, bh1, acc); acc = MFMA(ah1, bl1, acc); acc = MFMA(al1, bh1, acc);
    if (more) {
      ah1 = *(const bf8v*)(pa_h + nk +  512); al1 = *(const bf8v*)(pa_l + nk +  512);
      bh1 = *(const bf8v*)(pb_h + nk +  512); bl1 = *(const bf8v*)(pb_l + nk +  512);
    }
    acc = MFMA(ah2, bh2, acc); acc = MFMA(ah2, bl2, acc); acc = MFMA(al2, bh2, acc);
    if (more) {
      ah2 = *(const bf8v*)(pa_h + nk + 1024); al2 = *(const bf8v*)(pa_l + nk + 1024);
      bh2 = *(const bf8v*)(pb_h + nk + 1024); bl2 = *(const bf8v*)(pb_l + nk + 1024);
    }
    acc = MFMA(ah3, bh3, acc); acc = MFMA(ah3, bl3, acc); acc = MFMA(al3, bh3, acc);
    if (more) {
      ah3 = *(const bf8v*)(pa_h + nk + 1536); al3 = *(const bf8v*)(pa_l + nk + 1536);
      bh3 = *(const bf8v*)(pb_h + nk + 1536); bl3 = *(const bf8v*)(pb_l + nk + 1536);
    }
  }
}

// C/D mapping (HW-verified): col = lane&31, row = (reg&3)+8*(reg>>2)+4*(lane>>5)
#define CD_ROW(rr, g) (((rr) & 3) + 8 * ((rr) >> 2) + 4 * (g))

// ---------------- enc_att: encatt = enc @ W_enc + b_enc ----------------
__global__ __launch_bounds__(256) void menc_att(
    const ushort_t* __restrict__ Ahi, const ushort_t* __restrict__ Alo,
    const ushort_t* __restrict__ Whi, const ushort_t* __restrict__ Wlo,
    const float* __restrict__ benc, float* __restrict__ encatt)
{
  int w = threadIdx.x >> 6, lane = threadIdx.x & 63;
  int mt = blockIdx.y;                 // 196 m-tiles
  int ct = blockIdx.x * 4 + w;         // 16 col-tiles
  const ushort_t* pa_h = Ahi + ((size_t)mt * 128) * 512 + lane * 8;
  const ushort_t* pa_l = Alo + ((size_t)mt * 128) * 512 + lane * 8;
  const ushort_t* pb_h = Whi + ((size_t)ct * 128) * 512 + lane * 8;
  const ushort_t* pb_l = Wlo + ((size_t)ct * 128) * 512 + lane * 8;
  f16v acc = (f16v)(0.0f);
  mfma_pipe_frag(pa_h, pa_l, pb_h, pb_l, 32, acc);
  int r = lane & 31, g = lane >> 5;
  int n = ct * 32 + r;
  float bn = benc[n];
#pragma unroll
  for (int rr = 0; rr < 16; ++rr)
    encatt[(size_t)(mt * 32 + CD_ROW(rr, g)) * 512 + n] = acc[rr] + bn;
}

// ---------------- k1: dec_gate = h @ [W_dec | W_fb] ----------------
__global__ __launch_bounds__(256) void mk1(
    const ushort_t* __restrict__ hhi, const ushort_t* __restrict__ hlo,
    const ushort_t* __restrict__ W1hi, const ushort_t* __restrict__ W1lo,
    float* __restrict__ dec_gate)
{
  int w = threadIdx.x >> 6, lane = threadIdx.x & 63;
  int ct = blockIdx.x * 4 + w;         // 80 col-tiles
  const ushort_t* pa_h = hhi + lane * 8;
  const ushort_t* pa_l = hlo + lane * 8;
  const ushort_t* pb_h = W1hi + ((size_t)ct * 32) * 512 + lane * 8;
  const ushort_t* pb_l = W1lo + ((size_t)ct * 32) * 512 + lane * 8;
  f16v acc = (f16v)(0.0f);
  mfma_pipe_frag(pa_h, pa_l, pb_h, pb_l, 8, acc);
  int r = lane & 31, g = lane >> 5;
  int n = ct * 32 + r;
#pragma unroll
  for (int rr = 0; rr < 16; ++rr)
    dec_gate[CD_ROW(rr, g) * 2560 + n] = acc[rr];
}

// ---------------- k3: P2[s] = partial of x(=[aweg|h]) @ W3 ----------------
__global__ __launch_bounds__(256) void mk3(
    const ushort_t* __restrict__ xhi, const ushort_t* __restrict__ xlo,
    const ushort_t* __restrict__ W3hi, const ushort_t* __restrict__ W3lo,
    float* __restrict__ P2)
{
  int w = threadIdx.x >> 6, lane = threadIdx.x & 63;
  int ct = blockIdx.x * 4 + w;         // 64 col-tiles
  int s = blockIdx.y;                  // 8 k-slices of 20 chunks
  const ushort_t* pa_h = xhi + ((size_t)s * 20) * 512 + lane * 8;
  const ushort_t* pa_l = xlo + ((size_t)s * 20) * 512 + lane * 8;
  const ushort_t* pb_h = W3hi + ((size_t)ct * 160 + s * 20) * 512 + lane * 8;
  const ushort_t* pb_l = W3lo + ((size_t)ct * 160 + s * 20) * 512 + lane * 8;
  f16v acc = (f16v)(0.0f);
  mfma_pipe_frag(pa_h, pa_l, pb_h, pb_l, 5, acc);
  int r = lane & 31, g = lane >> 5;
  int n = ct * 32 + r;
#pragma unroll
  for (int rr = 0; rr < 16; ++rr)
    P2[(size_t)s * (32 * 2048) + CD_ROW(rr, g) * 2048 + n] = acc[rr];
}

// ---------------- km: preds(t) [0..249] + k1(t+1) [250..269] ----------------
__global__ __launch_bounds__(256) void mkm(
    const ushort_t* __restrict__ hhi, const ushort_t* __restrict__ hlo,
    const ushort_t* __restrict__ Wfchi, const ushort_t* __restrict__ Wfclo,
    const float* __restrict__ bfc, const int* __restrict__ clen,
    float* __restrict__ outp, int t,
    const ushort_t* __restrict__ W1hi, const ushort_t* __restrict__ W1lo,
    float* __restrict__ dec_gate, int do_k1)
{
  int bid = blockIdx.x;
  int w = threadIdx.x >> 6, lane = threadIdx.x & 63;
  int r = lane & 31, g = lane >> 5;
  const ushort_t* pa_h = hhi + lane * 8;
  const ushort_t* pa_l = hlo + lane * 8;
  if (bid < 250) {
    int ct = bid * 4 + w;              // 1000 col-tiles of Wfc
    const ushort_t* pb_h = Wfchi + ((size_t)ct * 32) * 512 + lane * 8;
    const ushort_t* pb_l = Wfclo + ((size_t)ct * 32) * 512 + lane * 8;
    f16v acc = (f16v)(0.0f);
    mfma_pipe_frag(pa_h, pa_l, pb_h, pb_l, 8, acc);
    int n = ct * 32 + r;
    float bn = bfc[n];
#pragma unroll
    for (int rr = 0; rr < 16; ++rr) {
      int b = CD_ROW(rr, g);
      bool act = clen[b] - 1 > t;
      outp[(size_t)b * (TS * VOC) + (size_t)t * VOC + n] = act ? (acc[rr] + bn) : 0.f;
    }
  } else if (do_k1) {
    int ct = (bid - 250) * 4 + w;      // 80 col-tiles of W1
    const ushort_t* pb_h = W1hi + ((size_t)ct * 32) * 512 + lane * 8;
    const ushort_t* pb_l = W1lo + ((size_t)ct * 32) * 512 + lane * 8;
    f16v acc = (f16v)(0.0f);
    mfma_pipe_frag(pa_h, pa_l, pb_h, pb_l, 8, acc);
    int n = ct * 32 + r;
#pragma unroll
    for (int rr = 0; rr < 16; ++rr)
      dec_gate[CD_ROW(rr, g) * 2560 + n] = acc[rr];
  }
}

// ---------------- conversions into frag layout ----------------
// enc [6272][2048] f32 -> A-frag (196 m-tiles, nkc=128)
__global__ __launch_bounds__(256) void convA_frag(
    const float* __restrict__ src, ushort_t* __restrict__ dhi, ushort_t* __restrict__ dlo)
{
  int mt = blockIdx.x;
  int kc = blockIdx.y * 4 + (threadIdx.x >> 6);
  int l = threadIdx.x & 63;
  int r = l & 31, g = l >> 5;
  const float* s = src + (size_t)(mt * 32 + r) * 2048 + kc * 16 + g * 8;
  float4 v0 = *(const float4*)s, v1 = *(const float4*)(s + 4);
  ushort4 h0, l0, h1, l1;
  h0.x = f2bf(v0.x); l0.x = f2bf(v0.x - bf2f(h0.x));
  h0.y = f2bf(v0.y); l0.y = f2bf(v0.y - bf2f(h0.y));
  h0.z = f2bf(v0.z); l0.z = f2bf(v0.z - bf2f(h0.z));
  h0.w = f2bf(v0.w); l0.w = f2bf(v0.w - bf2f(h0.w));
  h1.x = f2bf(v1.x); l1.x = f2bf(v1.x - bf2f(h1.x));
  h1.y = f2bf(v1.y); l1.y = f2bf(v1.y - bf2f(h1.y));
  h1.z = f2bf(v1.z); l1.z = f2bf(v1.z - bf2f(h1.z));
  h1.w = f2bf(v1.w); l1.w = f2bf(v1.w - bf2f(h1.w));
  size_t off = ((size_t)mt * 128 + kc) * 512 + (size_t)l * 8;
  *(ushort4*)&dhi[off] = h0; *(ushort4*)&dhi[off + 4] = h1;
  *(ushort4*)&dlo[off] = l0; *(ushort4*)&dlo[off + 4] = l1;
}

// W [K][N] f32 -> B-frag tiles (dst chunk count nkc_dst, chunk offset kc_off)
__global__ __launch_bounds__(256) void convT_frag(
    const float* __restrict__ src, int N,
    ushort_t* __restrict__ dhi, ushort_t* __restrict__ dlo,
    int nkc_dst, int kc_off)
{
  int ct = blockIdx.x;
  int kc = blockIdx.y * 4 + (threadIdx.x >> 6);
  int l = threadIdx.x & 63;
  int c = l & 31, g = l >> 5;
  const float* s = src + (size_t)(kc * 16 + g * 8) * N + ct * 32 + c;
  ushort_t hi8[8], lo8[8];
#pragma unroll
  for (int e = 0; e < 8; ++e) {
    float f = s[(size_t)e * N];
    hi8[e] = f2bf(f); lo8[e] = f2bf(f - bf2f(hi8[e]));
  }
  size_t off = ((size_t)ct * nkc_dst + kc_off + kc) * 512 + (size_t)l * 8;
  *(ushort4*)&dhi[off]     = make_ushort4(hi8[0], hi8[1], hi8[2], hi8[3]);
  *(ushort4*)&dhi[off + 4] = make_ushort4(hi8[4], hi8[5], hi8[6], hi8[7]);
  *(ushort4*)&dlo[off]     = make_ushort4(lo8[0], lo8[1], lo8[2], lo8[3]);
  *(ushort4*)&dlo[off + 4] = make_ushort4(lo8[4], lo8[5], lo8[6], lo8[7]);
}

// ---------------- avg over P ----------------
__global__ __launch_bounds__(256) void avgk(const float* __restrict__ enc, float* __restrict__ avg)
{
  int idx = blockIdx.x * 256 + threadIdx.x;   // 32*2048
  int b = idx >> 11, e = idx & 2047;
  float s = 0.f;
  for (int p = 0; p < NP; ++p) s += enc[(size_t)(b * NP + p) * ENC + e];
  avg[idx] = s * (1.f / 196.f);
}

// ---------------- generic 64x64 f32 GEMM (prologue only) ----------------
__global__ __launch_bounds__(256) void gemm64(
    const float* __restrict__ A, const float* __restrict__ W,
    const float* __restrict__ bias, float* __restrict__ C,
    int M, int N, int K)
{
  __shared__ float As[16][68];
  __shared__ float Ws[16][68];
  const int tid = threadIdx.x;
  const int tx = tid & 15, ty = tid >> 4;
  const int m0 = blockIdx.y * 64, n0 = blockIdx.x * 64;
  const int lm = tid >> 2, lk = (tid & 3) * 4;
  const int wk = tid >> 4, wn = (tid & 15) * 4;
  float acc[4][4] = {};
  for (int k0 = 0; k0 < K; k0 += 16) {
    float4 av = make_float4(0.f, 0.f, 0.f, 0.f);
    if (m0 + lm < M) av = *(const float4*)&A[(size_t)(m0 + lm) * K + k0 + lk];
    As[lk + 0][lm] = av.x; As[lk + 1][lm] = av.y; As[lk + 2][lm] = av.z; As[lk + 3][lm] = av.w;
    *(float4*)&Ws[wk][wn] = *(const float4*)&W[(size_t)(k0 + wk) * N + n0 + wn];
    __syncthreads();
#pragma unroll
    for (int k = 0; k < 16; ++k) {
      float a_[4], w_[4];
#pragma unroll
      for (int i = 0; i < 4; ++i) a_[i] = As[k][ty * 4 + i];
#pragma unroll
      for (int j = 0; j < 4; ++j) w_[j] = Ws[k][tx * 4 + j];
#pragma unroll
      for (int i = 0; i < 4; ++i)
#pragma unroll
        for (int j = 0; j < 4; ++j) acc[i][j] += a_[i] * w_[j];
    }
    __syncthreads();
  }
#pragma unroll
  for (int i = 0; i < 4; ++i) {
    int m = m0 + ty * 4 + i;
    if (m < M) {
#pragma unroll
      for (int j = 0; j < 4; ++j) {
        int n = n0 + tx * 4 + j;
        C[(size_t)m * N + n] = acc[i][j] + (bias ? bias[n] : 0.f);
      }
    }
  }
}

// ---------- embedding-gathered GEMM (prologue) ----------
__global__ __launch_bounds__(256) void gemm_emb(
    const float* __restrict__ Emb, const int* __restrict__ caps,
    const float* __restrict__ W, const float* __restrict__ b1,
    const float* __restrict__ b2, float* __restrict__ C,
    int M, int N, int K)
{
  __shared__ float As[16][68];
  __shared__ float Ws[16][68];
  const int tid = threadIdx.x;
  const int tx = tid & 15, ty = tid >> 4;
  const int m0 = blockIdx.y * 64, n0 = blockIdx.x * 64;
  const int lm = tid >> 2, lk = (tid & 3) * 4;
  const int wk = tid >> 4, wn = (tid & 15) * 4;
  const int r = m0 + lm;
  const float* arow = nullptr;
  if (r < M) {
    int tt = r >> 5, bb = r & 31;  // row = t*32 + b
    arow = Emb + (size_t)caps[bb * LCAP + tt] * K;
  }
  float acc[4][4] = {};
  for (int k0 = 0; k0 < K; k0 += 16) {
    float4 av = make_float4(0.f, 0.f, 0.f, 0.f);
    if (arow) av = *(const float4*)&arow[k0 + lk];
    As[lk + 0][lm] = av.x; As[lk + 1][lm] = av.y; As[lk + 2][lm] = av.z; As[lk + 3][lm] = av.w;
    *(float4*)&Ws[wk][wn] = *(const float4*)&W[(size_t)(k0 + wk) * N + n0 + wn];
    __syncthreads();
#pragma unroll
    for (int k = 0; k < 16; ++k) {
      float a_[4], w_[4];
#pragma unroll
      for (int i = 0; i < 4; ++i) a_[i] = As[k][ty * 4 + i];
#pragma unroll
      for (int j = 0; j < 4; ++j) w_[j] = Ws[k][tx * 4 + j];
#pragma unroll
      for (int i = 0; i < 4; ++i)
#pragma unroll
        for (int j = 0; j < 4; ++j) acc[i][j] += a_[i] * w_[j];
    }
    __syncthreads();
  }
#pragma unroll
  for (int i = 0; i < 4; ++i) {
    int m = m0 + ty * 4 + i;
    if (m < M) {
#pragma unroll
      for (int j = 0; j < 4; ++j) {
        int n = n0 + tx * 4 + j;
        C[(size_t)m * N + n] = acc[i][j] + b1[n] + b2[n];
      }
    }
  }
}

// ---------------- h0 -> h frag + x frag (h cols) ----------------
__global__ __launch_bounds__(256) void hsplit_frag(
    const float* __restrict__ h0f,
    ushort_t* __restrict__ hhi, ushort_t* __restrict__ hlo,
    ushort_t* __restrict__ xhi, ushort_t* __restrict__ xlo)
{
  int idx = blockIdx.x * 256 + threadIdx.x;  // 2048: b*64 + dq
  int b = idx >> 6, dq = idx & 63, d0 = dq << 3;
  ushort4 h0v, h1v, l0v, l1v;
  ushort_t hh[8], hl[8];
#pragma unroll
  for (int j = 0; j < 8; ++j) {
    float v = h0f[b * 512 + d0 + j];
    hh[j] = f2bf(v); hl[j] = f2bf(v - bf2f(hh[j]));
  }
  h0v = make_ushort4(hh[0], hh[1], hh[2], hh[3]); h1v = make_ushort4(hh[4], hh[5], hh[6], hh[7]);
  l0v = make_ushort4(hl[0], hl[1], hl[2], hl[3]); l1v = make_ushort4(hl[4], hl[5], hl[6], hl[7]);
  int kc = d0 >> 4, g = (d0 >> 3) & 1;
  size_t off = ((size_t)kc * 64 + g * 32 + b) * 8;
  *(ushort4*)&hhi[off] = h0v; *(ushort4*)&hhi[off + 4] = h1v;
  *(ushort4*)&hlo[off] = l0v; *(ushort4*)&hlo[off + 4] = l1v;
  int xk0 = 2048 + d0;
  size_t offx = ((size_t)(xk0 >> 4) * 64 + g * 32 + b) * 8;
  *(ushort4*)&xhi[offx] = h0v; *(ushort4*)&xhi[offx + 4] = h1v;
  *(ushort4*)&xlo[offx] = l0v; *(ushort4*)&xlo[offx + 4] = l1v;
}

// ---------------- k2a: e + softmax per batch row ----------------
__global__ __launch_bounds__(256) void k2a_soft(
    const float* __restrict__ dec_gate, const float* __restrict__ bdec,
    const float* __restrict__ watt, const float* __restrict__ batt,
    const float* __restrict__ encatt, const int* __restrict__ clen,
    float* __restrict__ outa, float* __restrict__ al_ws, int t)
{
  int b = blockIdx.x, tid = threadIdx.x;
  __shared__ float dec_s[512], watt_s[512], red_s[256];
  for (int a = tid; a < 512; a += 256) {
    dec_s[a] = dec_gate[b * 2560 + a] + bdec[a];
    watt_s[a] = watt[a];
  }
  __syncthreads();
  float e = -1e30f;
  if (tid < NP) {
    const float* row = encatt + (size_t)(b * NP + tid) * 512;
    float acc = 0.f;
    for (int a = 0; a < 512; a += 4) {
      float4 ev = *(const float4*)&row[a];
      acc += fmaxf(ev.x + dec_s[a + 0], 0.f) * watt_s[a + 0];
      acc += fmaxf(ev.y + dec_s[a + 1], 0.f) * watt_s[a + 1];
      acc += fmaxf(ev.z + dec_s[a + 2], 0.f) * watt_s[a + 2];
      acc += fmaxf(ev.w + dec_s[a + 3], 0.f) * watt_s[a + 3];
    }
    e = acc + batt[0];
  }
  red_s[tid] = e;
  __syncthreads();
  for (int w = 128; w > 0; w >>= 1) {
    if (tid < w) red_s[tid] = fmaxf(red_s[tid], red_s[tid + w]);
    __syncthreads();
  }
  float m = red_s[0];
  __syncthreads();
  float ex = (tid < NP) ? expf(e - m) : 0.f;
  red_s[tid] = ex;
  __syncthreads();
  for (int w = 128; w > 0; w >>= 1) {
    if (tid < w) red_s[tid] += red_s[tid + w];
    __syncthreads();
  }
  float inv = 1.f / red_s[0];
  if (tid < NP) {
    float al = ex * inv;
    al_ws[b * NP + tid] = al;
    bool act = clen[b] - 1 > t;
    outa[(size_t)(b * TS + t) * NP + tid] = act ? al : 0.f;
  }
}

// ---------------- k2b: awe + gate -> x frag cols 0..2047 (grid 32 x 8) ----------------
__global__ __launch_bounds__(256) void k2b_awe(
    const float* __restrict__ al_ws, const float* __restrict__ dec_gate,
    const float* __restrict__ bfb, const float* __restrict__ enc,
    ushort_t* __restrict__ xhi, ushort_t* __restrict__ xlo)
{
  int b = blockIdx.x, ds = blockIdx.y, tid = threadIdx.x;
  __shared__ float al_s[196];
  __shared__ float part[4][64][4];
  if (tid < NP) al_s[tid] = al_ws[b * NP + tid];
  __syncthreads();
  int q = tid & 63, sp = tid >> 6;
  int d = ds * 256 + q * 4;
  float ax = 0.f, ay = 0.f, az = 0.f, aw = 0.f;
  int p0 = sp * 49;
#pragma unroll 7
  for (int p = p0; p < p0 + 49; ++p) {
    float al = al_s[p];
    float4 ev = *(const float4*)&enc[(size_t)(b * NP + p) * ENC + d];
    ax += al * ev.x; ay += al * ev.y; az += al * ev.z; aw += al * ev.w;
  }
  part[sp][q][0] = ax; part[sp][q][1] = ay; part[sp][q][2] = az; part[sp][q][3] = aw;
  __syncthreads();
  if (sp == 0) {
    ax = part[0][q][0] + part[1][q][0] + part[2][q][0] + part[3][q][0];
    ay = part[0][q][1] + part[1][q][1] + part[2][q][1] + part[3][q][1];
    az = part[0][q][2] + part[1][q][2] + part[2][q][2] + part[3][q][2];
    aw = part[0][q][3] + part[1][q][3] + part[2][q][3] + part[3][q][3];
    float4 gg = *(const float4*)&dec_gate[b * 2560 + 512 + d];
    float4 bb = *(const float4*)&bfb[d];
    float v0 = sigm(gg.x + bb.x) * ax;
    float v1 = sigm(gg.y + bb.y) * ay;
    float v2 = sigm(gg.z + bb.z) * az;
    float v3 = sigm(gg.w + bb.w) * aw;
    ushort4 hi, lo;
    hi.x = f2bf(v0); lo.x = f2bf(v0 - bf2f(hi.x));
    hi.y = f2bf(v1); lo.y = f2bf(v1 - bf2f(hi.y));
    hi.z = f2bf(v2); lo.z = f2bf(v2 - bf2f(hi.z));
    hi.w = f2bf(v3); lo.w = f2bf(v3 - bf2f(hi.w));
    // x frag write: k index = d (awe occupies k 0..2047)
    size_t off = ((size_t)(d >> 4) * 64 + ((d >> 3) & 1) * 32 + b) * 8 + (d & 7);
    *(ushort4*)&xhi[off] = hi;
    *(ushort4*)&xlo[off] = lo;
  }
}

// ---------------- k4: LSTM pointwise + state update (frag writes) ----------------
__global__ __launch_bounds__(256) void k4_lstm_frag(
    const float* __restrict__ P2, const float* __restrict__ embproj,
    const int* __restrict__ clen, float* __restrict__ c,
    ushort_t* __restrict__ hhi, ushort_t* __restrict__ hlo,
    ushort_t* __restrict__ xhi, ushort_t* __restrict__ xlo, int t)
{
  int idx = blockIdx.x * 256 + threadIdx.x;  // 2048: b*64 + dq
  int b = idx >> 6, dq = idx & 63, d0 = dq << 3;
  if (clen[b] - 1 <= t) return;              // inactive rows freeze
  const float* ep = embproj + (size_t)(t * 32 + b) * 2048;
  f4v i0 = *(const f4v*)&ep[d0],        i1 = *(const f4v*)&ep[d0 + 4];
  f4v f0 = *(const f4v*)&ep[512 + d0],  f1 = *(const f4v*)&ep[512 + d0 + 4];
  f4v g0 = *(const f4v*)&ep[1024 + d0], g1 = *(const f4v*)&ep[1024 + d0 + 4];
  f4v o0 = *(const f4v*)&ep[1536 + d0], o1 = *(const f4v*)&ep[1536 + d0 + 4];
#pragma unroll
  for (int s = 0; s < 8; ++s) {
    const float* p2 = P2 + (size_t)s * 65536 + b * 2048;
    i0 += *(const f4v*)&p2[d0];        i1 += *(const f4v*)&p2[d0 + 4];
    f0 += *(const f4v*)&p2[512 + d0];  f1 += *(const f4v*)&p2[512 + d0 + 4];
    g0 += *(const f4v*)&p2[1024 + d0]; g1 += *(const f4v*)&p2[1024 + d0 + 4];
    o0 += *(const f4v*)&p2[1536 + d0]; o1 += *(const f4v*)&p2[1536 + d0 + 4];
  }
  f4v c0 = *(const f4v*)&c[b * 512 + d0], c1 = *(const f4v*)&c[b * 512 + d0 + 4];
  ushort_t hh[8], hl[8];
  f4v cn0, cn1;
#pragma unroll
  for (int j = 0; j < 8; ++j) {
    float iv = j < 4 ? i0[j] : i1[j - 4];
    float fv = j < 4 ? f0[j] : f1[j - 4];
    float gv = j < 4 ? g0[j] : g1[j - 4];
    float ov = j < 4 ? o0[j] : o1[j - 4];
    float cv = j < 4 ? c0[j] : c1[j - 4];
    float cn = sigm(fv) * cv + sigm(iv) * tanhf(gv);
    float hn = sigm(ov) * tanhf(cn);
    if (j < 4) cn0[j] = cn; else cn1[j - 4] = cn;
    hh[j] = f2bf(hn); hl[j] = f2bf(hn - bf2f(hh[j]));
  }
  *(f4v*)&c[b * 512 + d0] = cn0; *(f4v*)&c[b * 512 + d0 + 4] = cn1;
  ushort4 h0v = make_ushort4(hh[0], hh[1], hh[2], hh[3]);
  ushort4 h1v = make_ushort4(hh[4], hh[5], hh[6], hh[7]);
  ushort4 l0v = make_ushort4(hl[0], hl[1], hl[2], hl[3]);
  ushort4 l1v = make_ushort4(hl[4], hl[5], hl[6], hl[7]);
  int kc = d0 >> 4, g = (d0 >> 3) & 1;
  size_t off = ((size_t)kc * 64 + g * 32 + b) * 8;
  *(ushort4*)&hhi[off] = h0v; *(ushort4*)&hhi[off + 4] = h1v;
  *(ushort4*)&hlo[off] = l0v; *(ushort4*)&hlo[off + 4] = l1v;
  int xk0 = 2048 + d0;
  size_t offx = ((size_t)(xk0 >> 4) * 64 + g * 32 + b) * 8;
  *(ushort4*)&xhi[offx] = h0v; *(ushort4*)&xhi[offx + 4] = h1v;
  *(ushort4*)&xlo[offx] = l0v; *(ushort4*)&xlo[offx + 4] = l1v;
}

// =====================================================================
extern "C" void kernel_launch(void* const* d_in, const int* in_sizes, int n_in,
                              void* d_out, int out_size, void* d_ws, size_t ws_size,
                              hipStream_t stream)
{
  (void)in_sizes; (void)n_in; (void)out_size; (void)ws_size;
  const float* enc   = (const float*)d_in[0];
  const int*   caps  = (const int*)d_in[1];
  const int*   clen  = (const int*)d_in[2];
  const float* emb   = (const float*)d_in[3];
  const float* W_enc = (const float*)d_in[4];
  const float* b_enc = (const float*)d_in[5];
  const float* W_dec = (const float*)d_in[6];
  const float* b_dec = (const float*)d_in[7];
  const float* w_att = (const float*)d_in[8];
  const float* b_att = (const float*)d_in[9];
  const float* W_ih  = (const float*)d_in[10];
  const float* b_ih  = (const float*)d_in[11];
  const float* W_hh  = (const float*)d_in[12];
  const float* b_hh  = (const float*)d_in[13];
  const float* W_h   = (const float*)d_in[14];
  const float* b_h   = (const float*)d_in[15];
  const float* W_c   = (const float*)d_in[16];
  const float* b_c   = (const float*)d_in[17];
  const float* W_fb  = (const float*)d_in[18];
  const float* b_fb  = (const float*)d_in[19];
  const float* W_fc  = (const float*)d_in[20];
  const float* b_fc  = (const float*)d_in[21];

  float* out_preds = (float*)d_out;
  float* out_alpha = out_preds + (size_t)NB * TS * VOC;

  // ---------- workspace layout (total = 173,539,328 bytes, proven to fit) ----------
  char* p = (char*)d_ws;
  float* encatt   = (float*)p;            p += 12845056;   // 6272*512 f32
  float* embproj  = (float*)p;            p += 10223616;   // 1248*2048 f32
  float* P2buf    = (float*)p;            p += 2097152;    // 8*32*2048 f32
  float* dec_gate = (float*)p;            p += 327680;     // 32*2560 f32
  // region A: avg (prologue-only) overlapped by x_lo frag (loop)
  float* avg      = (float*)p;
  ushort_t* x_lo  = (ushort_t*)p;         p += 262144;
  float* h0f      = (float*)p;            p += 65536;      // 32*512 f32
  float* cbuf     = (float*)p;            p += 65536;      // 32*512 f32
  // region B: al_ws + h frag + x_hi frag
  float* al_ws    = (float*)p;            p += 25088;      // 32*196 f32
  ushort_t* h_hi  = (ushort_t*)p;         p += 32768;      // 32*512 bf16 frag
  ushort_t* h_lo  = (ushort_t*)p;         p += 32768;
  ushort_t* x_hi  = (ushort_t*)p;         p += 163840;     // 32*2560 bf16 frag
  p += 262144 - 25088 - 32768 - 32768 - 163840;
  ushort_t* e_hi  = (ushort_t*)p;         p += 25690112;   // enc frag
  ushort_t* e_lo  = (ushort_t*)p;         p += 25690112;
  ushort_t* We_hi = (ushort_t*)p;         p += 2097152;    // 16 tiles x 128 kc
  ushort_t* We_lo = (ushort_t*)p;         p += 2097152;
  ushort_t* W1_hi = (ushort_t*)p;         p += 2621440;    // 80 tiles x 32 kc
  ushort_t* W1_lo = (ushort_t*)p;         p += 2621440;
  ushort_t* W3_hi = (ushort_t*)p;         p += 10485760;   // 64 tiles x 160 kc
  ushort_t* W3_lo = (ushort_t*)p;         p += 10485760;
  ushort_t* Wf_hi = (ushort_t*)p;         p += 32768000;   // 1000 tiles x 32 kc
  ushort_t* Wf_lo = (ushort_t*)p;         p += 32768000;

  // ---------------- prologue ----------------
  avgk<<<dim3(256), 256, 0, stream>>>(enc, avg);
  gemm64<<<dim3(8, 1), 256, 0, stream>>>(avg, W_h, b_h, h0f, 32, 512, 2048);
  gemm64<<<dim3(8, 1), 256, 0, stream>>>(avg, W_c, b_c, cbuf, 32, 512, 2048);
  convA_frag<<<dim3(196, 32), 256, 0, stream>>>(enc, e_hi, e_lo);
  convT_frag<<<dim3(16, 32), 256, 0, stream>>>(W_enc, 512, We_hi, We_lo, 128, 0);
  convT_frag<<<dim3(16, 8), 256, 0, stream>>>(W_dec, 512, W1_hi, W1_lo, 32, 0);
  convT_frag<<<dim3(64, 8), 256, 0, stream>>>(W_fb, 2048,
      W1_hi + (size_t)16 * 32 * 512, W1_lo + (size_t)16 * 32 * 512, 32, 0);
  convT_frag<<<dim3(64, 32), 256, 0, stream>>>(W_ih + (size_t)512 * 2048, 2048,
      W3_hi, W3_lo, 160, 0);
  convT_frag<<<dim3(64, 8), 256, 0, stream>>>(W_hh, 2048, W3_hi, W3_lo, 160, 128);
  convT_frag<<<dim3(1000, 8), 256, 0, stream>>>(W_fc, VOC, Wf_hi, Wf_lo, 32, 0);

  menc_att<<<dim3(4, 196), 256, 0, stream>>>(e_hi, e_lo, We_hi, We_lo, b_enc, encatt);
  gemm_emb<<<dim3(32, 20), 256, 0, stream>>>(emb, caps, W_ih, b_ih, b_hh, embproj, 1248, 2048, 512);
  hsplit_frag<<<dim3(8), 256, 0, stream>>>(h0f, h_hi, h_lo, x_hi, x_lo);
  mk1<<<dim3(20), 256, 0, stream>>>(h_hi, h_lo, W1_hi, W1_lo, dec_gate);

  // ---------------- decode loop ----------------
  for (int t = 0; t < TS; ++t) {
    k2a_soft<<<dim3(32), 256, 0, stream>>>(dec_gate, b_dec, w_att, b_att,
                                           encatt, clen, out_alpha, al_ws, t);
    k2b_awe<<<dim3(32, 8), 256, 0, stream>>>(al_ws, dec_gate, b_fb, enc, x_hi, x_lo);
    mk3<<<dim3(16, 8), 256, 0, stream>>>(x_hi, x_lo, W3_hi, W3_lo, P2buf);
    k4_lstm_frag<<<dim3(8), 256, 0, stream>>>(P2buf, embproj, clen, cbuf,
                                              h_hi, h_lo, x_hi, x_lo, t);
    mkm<<<dim3(270), 256, 0, stream>>>(h_hi, h_lo, Wf_hi, Wf_lo, b_fc, clen, out_preds, t,
                                       W1_hi, W1_lo, dec_gate, (t < TS - 1) ? 1 : 0);
  }
}